// Round 1
// baseline (2936.214 us; speedup 1.0000x reference)
//
#include <hip/hip_runtime.h>
#include <cstdint>
#include <cstddef>

#define S_  512
#define B_  32
#define D_  512
#define FF_ 2048
#define L_  6
#define O_  1000
#define M_  (B_*S_)     // 16384 rows of activations
#define G_  256         // B*H attention groups
#define DH_ 64

typedef __attribute__((ext_vector_type(8))) short bf16x8;
typedef __attribute__((ext_vector_type(4))) float f32x4;

__device__ __forceinline__ unsigned short f2bf(float f) {
  unsigned int u = __builtin_bit_cast(unsigned int, f);
  u = (u + 0x7fffu + ((u >> 16) & 1u)) >> 16;
  return (unsigned short)u;
}

__device__ __forceinline__ void gload_lds16(const void* g, void* l) {
  __builtin_amdgcn_global_load_lds(
      (const __attribute__((address_space(1))) unsigned int*)g,
      (__attribute__((address_space(3))) unsigned int*)l, 16, 0, 0);
}

// ---------------- positional encoding table [512][512] f32 ----------------
__global__ void pe_kernel(float* __restrict__ pe) {
  int i = blockIdx.x * 256 + threadIdx.x;   // 512*512 total
  int s = i >> 9, d = i & 511;
  double de = (double)(d & ~1);
  double ang = (double)s * exp(de * (-9.210340371976184 / 512.0)); // s / 10000^(de/512)
  pe[i] = (d & 1) ? (float)cos(ang) : (float)sin(ang);
}

// ------------- transpose-convert W [z][K][N] f32 -> Wt [z][N][K] bf16 -------------
__global__ void wconv_kernel(const float* __restrict__ W, unsigned short* __restrict__ Wt,
                             int K, int N) {
  __shared__ float tile[32][33];
  size_t zoff = (size_t)blockIdx.z * K * N;
  const float* Wl = W + zoff;
  unsigned short* Wtl = Wt + zoff;
  int k0 = blockIdx.x * 32, n0 = blockIdx.y * 32;
  int c = threadIdx.x & 31, rb = threadIdx.x >> 5;
#pragma unroll
  for (int i = 0; i < 4; ++i) {
    int r = rb + i * 8;
    tile[r][c] = Wl[(size_t)(k0 + r) * N + n0 + c];
  }
  __syncthreads();
#pragma unroll
  for (int i = 0; i < 4; ++i) {
    int r = rb + i * 8;
    Wtl[(size_t)(n0 + r) * K + k0 + c] = f2bf(tile[c][r]);
  }
}

// ------------- embedding + PE: out[b][s][:] = emb[x[s][b]] + pe[s] -------------
__global__ void embed_kernel(const int* __restrict__ x, const float* __restrict__ emb,
                             const float* __restrict__ pe,
                             float* __restrict__ xf, unsigned short* __restrict__ xb) {
  int bi = blockIdx.x;            // s*B + b
  int s = bi / B_, b = bi % B_;
  int tok = x[s * B_ + b];
  int d = threadIdx.x * 4;
  float4 e = *(const float4*)(emb + (size_t)tok * D_ + d);
  float4 p = *(const float4*)(pe + (size_t)s * D_ + d);
  float v0 = e.x + p.x, v1 = e.y + p.y, v2 = e.z + p.z, v3 = e.w + p.w;
  size_t o = ((size_t)b * S_ + s) * D_ + d;
  *(float4*)(xf + o) = make_float4(v0, v1, v2, v3);
  ushort4 u; u.x = f2bf(v0); u.y = f2bf(v1); u.z = f2bf(v2); u.w = f2bf(v3);
  *(ushort4*)(xb + o) = u;
}

// ------------- bf16 MFMA GEMM: C[M][N] = A[M][K] @ Bt[N][K]^T + bias (+resid)(+relu) -------------
__global__ __launch_bounds__(256) void gemm_kernel(
    const unsigned short* __restrict__ A, const unsigned short* __restrict__ Bt,
    const float* __restrict__ bias, const float* __restrict__ resid,
    unsigned short* __restrict__ outb, float* __restrict__ outf,
    int K, int N, int relu) {
  __shared__ unsigned short As[128 * 32];
  __shared__ unsigned short Bs[128 * 32];
  int tid = threadIdx.x, lane = tid & 63, wid = tid >> 6;
  int m0 = blockIdx.y * 128, n0 = blockIdx.x * 128;
  int wm = wid >> 1, wn = wid & 1;
  f32x4 acc[4][4];
#pragma unroll
  for (int mi = 0; mi < 4; ++mi)
#pragma unroll
    for (int ni = 0; ni < 4; ++ni) acc[mi][ni] = (f32x4)0.0f;

  int srow = lane >> 2, scol = (lane & 3) * 8;
  const unsigned short* Abase = A + (size_t)m0 * K;
  const unsigned short* Bbase = Bt + (size_t)n0 * K;
  int c16 = lane & 15, hi = lane >> 4;
  int koff = hi * 8;
  int nk = K >> 5;
  for (int kt = 0; kt < nk; ++kt) {
    int k0 = kt * 32;
#pragma unroll
    for (int i = 0; i < 2; ++i) {
      int c = wid * 2 + i;
      gload_lds16(Abase + (size_t)(c * 16 + srow) * K + k0 + scol, (char*)As + c * 1024);
      gload_lds16(Bbase + (size_t)(c * 16 + srow) * K + k0 + scol, (char*)Bs + c * 1024);
    }
    __syncthreads();
    bf16x8 af[4], bfr[4];
    int arow = wm * 64 + c16, brow = wn * 64 + c16;
#pragma unroll
    for (int mi = 0; mi < 4; ++mi) af[mi] = *(const bf16x8*)&As[(arow + mi * 16) * 32 + koff];
#pragma unroll
    for (int ni = 0; ni < 4; ++ni) bfr[ni] = *(const bf16x8*)&Bs[(brow + ni * 16) * 32 + koff];
#pragma unroll
    for (int mi = 0; mi < 4; ++mi)
#pragma unroll
      for (int ni = 0; ni < 4; ++ni)
        acc[mi][ni] = __builtin_amdgcn_mfma_f32_16x16x32_bf16(af[mi], bfr[ni], acc[mi][ni], 0, 0, 0);
    __syncthreads();
  }
  int r0 = hi * 4;
#pragma unroll
  for (int ni = 0; ni < 4; ++ni) {
    int col = n0 + wn * 64 + ni * 16 + c16;
    float bv = bias[col];
#pragma unroll
    for (int mi = 0; mi < 4; ++mi) {
      int rowb = m0 + wm * 64 + mi * 16 + r0;
#pragma unroll
      for (int r = 0; r < 4; ++r) {
        int row = rowb + r;
        float v = acc[mi][ni][r] + bv;
        if (resid) v += resid[(size_t)row * N + col];
        if (relu) v = fmaxf(v, 0.0f);
        if (outf) outf[(size_t)row * N + col] = v;
        if (outb) outb[(size_t)row * N + col] = f2bf(v);
      }
    }
  }
}

// ------------- flash attention over 256 groups of [512, 64] -------------
#define KP  72   // Q/K LDS row stride (bf16)
#define VTP 40   // V^T LDS row stride
#define PP  40   // P LDS row stride
__global__ __launch_bounds__(256) void attn_kernel(
    const unsigned short* __restrict__ Q, const unsigned short* __restrict__ Kb,
    const unsigned short* __restrict__ Vb, unsigned short* __restrict__ Ctx) {
  __shared__ unsigned short Ql[128 * KP];
  __shared__ unsigned short Kl[32 * KP];
  __shared__ unsigned short Vt[64 * VTP];
  __shared__ unsigned short Pl[4][32 * PP];
  int g = blockIdx.y;
  int q0 = blockIdx.x * 128;
  const unsigned short* Qg = Q + ((size_t)g * 512 + q0) * 64;
  const unsigned short* Kg = Kb + (size_t)g * 512 * 64;
  const unsigned short* Vg = Vb + (size_t)g * 512 * 64;
  int tid = threadIdx.x, lane = tid & 63, wid = tid >> 6;
  int c16 = lane & 15, hi = lane >> 4, r0 = hi * 4;
  int wq0 = wid * 32;
  const float scale = 0.125f;

  // load Q tile 128x64 into padded LDS
#pragma unroll
  for (int i = 0; i < 4; ++i) {
    int oct = tid + i * 256;
    int row = oct >> 3, oc = (oct & 7) * 8;
    bf16x8 v = *(const bf16x8*)(Qg + (size_t)row * 64 + oc);
    *(bf16x8*)&Ql[row * KP + oc] = v;
  }

  float mr[2][4], ls[2][4];
  f32x4 cacc[2][4];
#pragma unroll
  for (int mi = 0; mi < 2; ++mi)
#pragma unroll
    for (int r = 0; r < 4; ++r) { mr[mi][r] = -1e30f; ls[mi][r] = 0.0f; }
#pragma unroll
  for (int mi = 0; mi < 2; ++mi)
#pragma unroll
    for (int nd = 0; nd < 4; ++nd) cacc[mi][nd] = (f32x4)0.0f;

  __syncthreads();
  for (int kt = 0; kt < 16; ++kt) {
    __syncthreads();   // previous iter reads done
    {
      int row = tid >> 3, oc = (tid & 7) * 8;
      bf16x8 kv = *(const bf16x8*)(Kg + (size_t)(kt * 32 + row) * 64 + oc);
      *(bf16x8*)&Kl[row * KP + oc] = kv;
      bf16x8 vv = *(const bf16x8*)(Vg + (size_t)(kt * 32 + row) * 64 + oc);
#pragma unroll
      for (int i = 0; i < 8; ++i) Vt[(oc + i) * VTP + row] = (unsigned short)vv[i];
    }
    __syncthreads();   // staged tiles visible

    // QK^T: [32 q] x [32 j], K-dim = 64 (2 MFMA steps)
    f32x4 sacc[2][2];
#pragma unroll
    for (int mi = 0; mi < 2; ++mi)
#pragma unroll
      for (int nj = 0; nj < 2; ++nj) sacc[mi][nj] = (f32x4)0.0f;
#pragma unroll
    for (int ds_ = 0; ds_ < 2; ++ds_) {
      int ko = ds_ * 32 + hi * 8;
      bf16x8 q0f = *(const bf16x8*)&Ql[(wq0 + c16) * KP + ko];
      bf16x8 q1f = *(const bf16x8*)&Ql[(wq0 + 16 + c16) * KP + ko];
      bf16x8 k0f = *(const bf16x8*)&Kl[c16 * KP + ko];
      bf16x8 k1f = *(const bf16x8*)&Kl[(16 + c16) * KP + ko];
      sacc[0][0] = __builtin_amdgcn_mfma_f32_16x16x32_bf16(q0f, k0f, sacc[0][0], 0, 0, 0);
      sacc[0][1] = __builtin_amdgcn_mfma_f32_16x16x32_bf16(q0f, k1f, sacc[0][1], 0, 0, 0);
      sacc[1][0] = __builtin_amdgcn_mfma_f32_16x16x32_bf16(q1f, k0f, sacc[1][0], 0, 0, 0);
      sacc[1][1] = __builtin_amdgcn_mfma_f32_16x16x32_bf16(q1f, k1f, sacc[1][1], 0, 0, 0);
    }

    // online softmax (rows = hi*4+r within each 16-row frag; 16 lanes share a row set)
#pragma unroll
    for (int mi = 0; mi < 2; ++mi) {
      float tmax[4];
#pragma unroll
      for (int r = 0; r < 4; ++r) tmax[r] = fmaxf(sacc[mi][0][r], sacc[mi][1][r]);
#pragma unroll
      for (int m = 1; m < 16; m <<= 1)
#pragma unroll
        for (int r = 0; r < 4; ++r) tmax[r] = fmaxf(tmax[r], __shfl_xor(tmax[r], m));
#pragma unroll
      for (int r = 0; r < 4; ++r) {
        float mnew = fmaxf(mr[mi][r], tmax[r] * scale);
        float alpha = __expf(mr[mi][r] - mnew);
        mr[mi][r] = mnew;
        ls[mi][r] *= alpha;
#pragma unroll
        for (int nd = 0; nd < 4; ++nd) cacc[mi][nd][r] *= alpha;
      }
      float rsum[4] = {0.f, 0.f, 0.f, 0.f};
#pragma unroll
      for (int nj = 0; nj < 2; ++nj)
#pragma unroll
        for (int r = 0; r < 4; ++r) {
          float p = __expf(sacc[mi][nj][r] * scale - mr[mi][r]);
          rsum[r] += p;
          Pl[wid][(mi * 16 + r0 + r) * PP + nj * 16 + c16] = f2bf(p);
        }
#pragma unroll
      for (int m = 1; m < 16; m <<= 1)
#pragma unroll
        for (int r = 0; r < 4; ++r) rsum[r] += __shfl_xor(rsum[r], m);
#pragma unroll
      for (int r = 0; r < 4; ++r) ls[mi][r] += rsum[r];
    }
    __syncthreads();   // P visible

    // PV: ctx[32 q][64 dh] += P[32 q][32 j] @ V[32 j][64 dh]
#pragma unroll
    for (int mi = 0; mi < 2; ++mi) {
      bf16x8 pf = *(const bf16x8*)&Pl[wid][(mi * 16 + c16) * PP + hi * 8];
#pragma unroll
      for (int nd = 0; nd < 4; ++nd) {
        bf16x8 vf = *(const bf16x8*)&Vt[(nd * 16 + c16) * VTP + hi * 8];
        cacc[mi][nd] = __builtin_amdgcn_mfma_f32_16x16x32_bf16(pf, vf, cacc[mi][nd], 0, 0, 0);
      }
    }
  }

#pragma unroll
  for (int mi = 0; mi < 2; ++mi)
#pragma unroll
    for (int nd = 0; nd < 4; ++nd)
#pragma unroll
      for (int r = 0; r < 4; ++r) {
        float v = cacc[mi][nd][r] / ls[mi][r];
        int row = q0 + wq0 + mi * 16 + r0 + r;
        int col = nd * 16 + c16;
        Ctx[((size_t)g * 512 + row) * 64 + col] = f2bf(v);
      }
}

// ------------- LayerNorm over rows of 512, fp32 in, fp32+bf16 out -------------
__global__ __launch_bounds__(128) void ln_kernel(const float* __restrict__ X,
                                                 const float* __restrict__ g,
                                                 const float* __restrict__ b,
                                                 float* __restrict__ Yf,
                                                 unsigned short* __restrict__ Yb) {
  __shared__ float red[2], red2[2];
  int row = blockIdx.x, t = threadIdx.x;
  const float* xr = X + (size_t)row * 512;
  float4 v = *(const float4*)(xr + t * 4);
  float s = v.x + v.y + v.z + v.w;
#pragma unroll
  for (int m = 1; m < 64; m <<= 1) s += __shfl_xor(s, m);
  if ((t & 63) == 0) red[t >> 6] = s;
  __syncthreads();
  float mean = (red[0] + red[1]) * (1.0f / 512.0f);
  float d0 = v.x - mean, d1 = v.y - mean, d2 = v.z - mean, d3 = v.w - mean;
  float sq = d0 * d0 + d1 * d1 + d2 * d2 + d3 * d3;
#pragma unroll
  for (int m = 1; m < 64; m <<= 1) sq += __shfl_xor(sq, m);
  if ((t & 63) == 0) red2[t >> 6] = sq;
  __syncthreads();
  float var = (red2[0] + red2[1]) * (1.0f / 512.0f);
  float rstd = rsqrtf(var + 1e-5f);
  float4 gg = *(const float4*)(g + t * 4);
  float4 bb = *(const float4*)(b + t * 4);
  float y0 = d0 * rstd * gg.x + bb.x;
  float y1 = d1 * rstd * gg.y + bb.y;
  float y2 = d2 * rstd * gg.z + bb.z;
  float y3 = d3 * rstd * gg.w + bb.w;
  size_t o = (size_t)row * 512 + t * 4;
  *(float4*)(Yf + o) = make_float4(y0, y1, y2, y3);
  ushort4 u; u.x = f2bf(y0); u.y = f2bf(y1); u.z = f2bf(y2); u.w = f2bf(y3);
  *(ushort4*)(Yb + o) = u;
}

// ------------- final FC: out[32][1000] = act[32][262144] @ Wfc + bfc (split-K) -------------
#define KCH 1024
__global__ __launch_bounds__(256) void fc_part_kernel(const float* __restrict__ act,
                                                      const float* __restrict__ Wfc,
                                                      float* __restrict__ part) {
  __shared__ float al[32][256];
  int o = blockIdx.x * 256 + threadIdx.x;
  int kc = blockIdx.y;
  size_t k0 = (size_t)kc * KCH;
  float acc[32];
#pragma unroll
  for (int bb = 0; bb < 32; ++bb) acc[bb] = 0.0f;
  for (int sub = 0; sub < KCH / 256; ++sub) {
    __syncthreads();
    for (int i = threadIdx.x; i < 32 * 256; i += 256) {
      int bb = i >> 8, kk = i & 255;
      al[bb][kk] = act[(size_t)bb * 262144 + k0 + sub * 256 + kk];
    }
    __syncthreads();
    if (o < O_) {
      const float* wp = Wfc + (k0 + sub * 256) * O_ + o;
      for (int kk = 0; kk < 256; ++kk) {
        float w = wp[(size_t)kk * O_];
#pragma unroll
        for (int bb = 0; bb < 32; ++bb) acc[bb] = fmaf(al[bb][kk], w, acc[bb]);
      }
    }
  }
  if (o < O_) {
#pragma unroll
    for (int bb = 0; bb < 32; ++bb) part[((size_t)kc * 32 + bb) * O_ + o] = acc[bb];
  }
}

__global__ void fc_reduce_kernel(const float* __restrict__ part, const float* __restrict__ bfc,
                                 float* __restrict__ out) {
  int o = blockIdx.x * 256 + threadIdx.x;
  int b = blockIdx.y;
  if (o >= O_) return;
  float s = bfc[o];
  for (int c = 0; c < 256; ++c) s += part[((size_t)c * 32 + b) * O_ + o];
  out[(size_t)b * O_ + o] = s;
}

extern "C" void kernel_launch(void* const* d_in, const int* in_sizes, int n_in,
                              void* d_out, int out_size, void* d_ws, size_t ws_size,
                              hipStream_t stream) {
  const int*   x   = (const int*)d_in[0];
  const float* emb = (const float*)d_in[2];
  const float* Wq  = (const float*)d_in[3];
  const float* bq  = (const float*)d_in[4];
  const float* Wk  = (const float*)d_in[5];
  const float* bk  = (const float*)d_in[6];
  const float* Wv  = (const float*)d_in[7];
  const float* bv  = (const float*)d_in[8];
  const float* Wo  = (const float*)d_in[9];
  const float* bo  = (const float*)d_in[10];
  const float* g1  = (const float*)d_in[11];
  const float* bn1 = (const float*)d_in[12];
  const float* W1  = (const float*)d_in[13];
  const float* bf1 = (const float*)d_in[14];
  const float* W2  = (const float*)d_in[15];
  const float* bf2 = (const float*)d_in[16];
  const float* g2  = (const float*)d_in[17];
  const float* bn2 = (const float*)d_in[18];
  const float* Wfc = (const float*)d_in[19];
  const float* bfc = (const float*)d_in[20];
  float* out = (float*)d_out;

  char* ws = (char*)d_ws;
  size_t off = 0;
  auto take = [&](size_t bytes) { char* p = ws + off; off += (bytes + 255) & ~(size_t)255; return p; };
  float*          pe  = (float*)take((size_t)512 * 512 * 4);
  unsigned short* wqt = (unsigned short*)take((size_t)L_ * 512 * 512 * 2);
  unsigned short* wkt = (unsigned short*)take((size_t)L_ * 512 * 512 * 2);
  unsigned short* wvt = (unsigned short*)take((size_t)L_ * 512 * 512 * 2);
  unsigned short* wot = (unsigned short*)take((size_t)L_ * 512 * 512 * 2);
  unsigned short* w1t = (unsigned short*)take((size_t)L_ * 2048 * 512 * 2);
  unsigned short* w2t = (unsigned short*)take((size_t)L_ * 512 * 2048 * 2);
  float*          xf  = (float*)take((size_t)M_ * 512 * 4);
  unsigned short* xb  = (unsigned short*)take((size_t)M_ * 512 * 2);
  unsigned short* qb  = (unsigned short*)take((size_t)M_ * 512 * 2);
  unsigned short* kb  = (unsigned short*)take((size_t)M_ * 512 * 2);
  unsigned short* vb  = (unsigned short*)take((size_t)M_ * 512 * 2);
  unsigned short* cxb = (unsigned short*)take((size_t)M_ * 512 * 2);
  float*          tf  = (float*)take((size_t)M_ * 512 * 4);
  float*          hf  = (float*)take((size_t)M_ * 512 * 4);
  unsigned short* hb  = (unsigned short*)take((size_t)M_ * 512 * 2);
  unsigned short* f1b = qb;          // alias: q/k/v/ctx region (exactly 64 MiB) free during FFN
  float*          part = (float*)qb; // alias: free after last layer

  pe_kernel<<<1024, 256, 0, stream>>>(pe);
  wconv_kernel<<<dim3(16, 16, L_), 256, 0, stream>>>(Wq, wqt, 512, 512);
  wconv_kernel<<<dim3(16, 16, L_), 256, 0, stream>>>(Wk, wkt, 512, 512);
  wconv_kernel<<<dim3(16, 16, L_), 256, 0, stream>>>(Wv, wvt, 512, 512);
  wconv_kernel<<<dim3(16, 16, L_), 256, 0, stream>>>(Wo, wot, 512, 512);
  wconv_kernel<<<dim3(16, 64, L_), 256, 0, stream>>>(W1, w1t, 512, 2048);
  wconv_kernel<<<dim3(64, 16, L_), 256, 0, stream>>>(W2, w2t, 2048, 512);
  embed_kernel<<<M_, 128, 0, stream>>>(x, emb, pe, xf, xb);

  for (int l = 0; l < L_; ++l) {
    gemm_kernel<<<dim3(4, 128), 256, 0, stream>>>(xb, wqt + (size_t)l * 512 * 512, bq + l * 512,
                                                  nullptr, qb, nullptr, 512, 512, 0);
    gemm_kernel<<<dim3(4, 128), 256, 0, stream>>>(xb, wkt + (size_t)l * 512 * 512, bk + l * 512,
                                                  nullptr, kb, nullptr, 512, 512, 0);
    gemm_kernel<<<dim3(4, 128), 256, 0, stream>>>(xb, wvt + (size_t)l * 512 * 512, bv + l * 512,
                                                  nullptr, vb, nullptr, 512, 512, 0);
    attn_kernel<<<dim3(4, G_), 256, 0, stream>>>(qb, kb, vb, cxb);
    gemm_kernel<<<dim3(4, 128), 256, 0, stream>>>(cxb, wot + (size_t)l * 512 * 512, bo + l * 512,
                                                  xf, nullptr, tf, 512, 512, 0);
    ln_kernel<<<M_, 128, 0, stream>>>(tf, g1 + l * 512, bn1 + l * 512, hf, hb);
    gemm_kernel<<<dim3(16, 128), 256, 0, stream>>>(hb, w1t + (size_t)l * 2048 * 512, bf1 + l * 2048,
                                                   nullptr, f1b, nullptr, 512, 2048, 1);
    gemm_kernel<<<dim3(4, 128), 256, 0, stream>>>(f1b, w2t + (size_t)l * 512 * 2048, bf2 + l * 512,
                                                  hf, nullptr, tf, 2048, 512, 0);
    ln_kernel<<<M_, 128, 0, stream>>>(tf, g2 + l * 512, bn2 + l * 512, xf, xb);
  }

  fc_part_kernel<<<dim3(4, 256), 256, 0, stream>>>(xf, Wfc, part);
  fc_reduce_kernel<<<dim3(4, 32), 256, 0, stream>>>(part, bfc, out);
}

// Round 2
// 2556.705 us; speedup vs baseline: 1.1484x; 1.1484x over previous
//
#include <hip/hip_runtime.h>
#include <cstdint>
#include <cstddef>

#define S_  512
#define B_  32
#define D_  512
#define FF_ 2048
#define L_  6
#define O_  1000
#define M_  (B_*S_)     // 16384 rows of activations
#define G_  256         // B*H attention groups
#define DH_ 64

typedef __attribute__((ext_vector_type(8))) short bf16x8;
typedef __attribute__((ext_vector_type(4))) float f32x4;

__device__ __forceinline__ unsigned short f2bf(float f) {
  unsigned int u = __builtin_bit_cast(unsigned int, f);
  u = (u + 0x7fffu + ((u >> 16) & 1u)) >> 16;
  return (unsigned short)u;
}

__device__ __forceinline__ void gload_lds16(const void* g, void* l) {
  __builtin_amdgcn_global_load_lds(
      (const __attribute__((address_space(1))) unsigned int*)g,
      (__attribute__((address_space(3))) unsigned int*)l, 16, 0, 0);
}

// ---------------- positional encoding table [512][512] f32 ----------------
__global__ void pe_kernel(float* __restrict__ pe) {
  int i = blockIdx.x * 256 + threadIdx.x;   // 512*512 total
  int s = i >> 9, d = i & 511;
  double de = (double)(d & ~1);
  double ang = (double)s * exp(de * (-9.210340371976184 / 512.0)); // s / 10000^(de/512)
  pe[i] = (d & 1) ? (float)cos(ang) : (float)sin(ang);
}

// ------------- transpose-convert W [z][K][N] f32 -> Wt [z-stride ozs][N][K] bf16 -------------
__global__ void wconv_kernel(const float* __restrict__ W, unsigned short* __restrict__ Wt,
                             int K, int N, size_t ozs) {
  __shared__ float tile[32][33];
  const float* Wl = W + (size_t)blockIdx.z * K * N;
  unsigned short* Wtl = Wt + (size_t)blockIdx.z * ozs;
  int k0 = blockIdx.x * 32, n0 = blockIdx.y * 32;
  int c = threadIdx.x & 31, rb = threadIdx.x >> 5;
#pragma unroll
  for (int i = 0; i < 4; ++i) {
    int r = rb + i * 8;
    tile[r][c] = Wl[(size_t)(k0 + r) * N + n0 + c];
  }
  __syncthreads();
#pragma unroll
  for (int i = 0; i < 4; ++i) {
    int r = rb + i * 8;
    Wtl[(size_t)(n0 + r) * K + k0 + c] = f2bf(tile[c][r]);
  }
}

// ------------- embedding + PE: out[b][s][:] = emb[x[s][b]] + pe[s] -------------
__global__ void embed_kernel(const int* __restrict__ x, const float* __restrict__ emb,
                             const float* __restrict__ pe,
                             float* __restrict__ xf, unsigned short* __restrict__ xb) {
  int bi = blockIdx.x;            // s*B + b
  int s = bi / B_, b = bi % B_;
  int tok = x[s * B_ + b];
  int d = threadIdx.x * 4;
  float4 e = *(const float4*)(emb + (size_t)tok * D_ + d);
  float4 p = *(const float4*)(pe + (size_t)s * D_ + d);
  float v0 = e.x + p.x, v1 = e.y + p.y, v2 = e.z + p.z, v3 = e.w + p.w;
  size_t o = ((size_t)b * S_ + s) * D_ + d;
  *(float4*)(xf + o) = make_float4(v0, v1, v2, v3);
  ushort4 u; u.x = f2bf(v0); u.y = f2bf(v1); u.z = f2bf(v2); u.w = f2bf(v3);
  *(ushort4*)(xb + o) = u;
}

// ------------- bf16 MFMA GEMM, 128x128 tile, BK=64 (two linear [128][32] sub-tiles) -------------
// split=1: N logical 1536, cols [0,512) -> o0/b0, [512,1024) -> o1/b1, [1024,1536) -> o2/b2
__global__ __launch_bounds__(256) void gemm_kernel(
    const unsigned short* __restrict__ A, const unsigned short* __restrict__ Bt,
    const float* __restrict__ b0, const float* __restrict__ b1, const float* __restrict__ b2,
    unsigned short* __restrict__ o0, unsigned short* __restrict__ o1, unsigned short* __restrict__ o2,
    int K, int N, int relu, int split) {
  __shared__ unsigned short As[2 * 128 * 32];
  __shared__ unsigned short Bs[2 * 128 * 32];
  int tid = threadIdx.x, lane = tid & 63, wid = tid >> 6;
  int m0 = blockIdx.y * 128, n0 = blockIdx.x * 128;
  int wm = wid >> 1, wn = wid & 1;
  f32x4 acc[4][4];
#pragma unroll
  for (int mi = 0; mi < 4; ++mi)
#pragma unroll
    for (int ni = 0; ni < 4; ++ni) acc[mi][ni] = (f32x4)0.0f;

  int srow = lane >> 2, scol = (lane & 3) * 8;
  const unsigned short* Abase = A + (size_t)m0 * K;
  const unsigned short* Bbase = Bt + (size_t)n0 * K;
  int c16 = lane & 15, hi = lane >> 4;
  int koff = hi * 8;
  int arow = wm * 64 + c16, brow = wn * 64 + c16;
  int nk = K >> 6;
  for (int kt = 0; kt < nk; ++kt) {
    int k0 = kt * 64;
#pragma unroll
    for (int i = 0; i < 4; ++i) {
      int c = wid * 4 + i;
      int ks = c >> 3;
      int rl = (c & 7) * 16 + srow;
      int cc = k0 + ks * 32 + scol;
      gload_lds16(Abase + (size_t)rl * K + cc, (char*)As + c * 1024);
      gload_lds16(Bbase + (size_t)rl * K + cc, (char*)Bs + c * 1024);
    }
    __syncthreads();
#pragma unroll
    for (int ks = 0; ks < 2; ++ks) {
      bf16x8 af[4], bfr[4];
#pragma unroll
      for (int mi = 0; mi < 4; ++mi) af[mi] = *(const bf16x8*)&As[ks * 4096 + (arow + mi * 16) * 32 + koff];
#pragma unroll
      for (int ni = 0; ni < 4; ++ni) bfr[ni] = *(const bf16x8*)&Bs[ks * 4096 + (brow + ni * 16) * 32 + koff];
#pragma unroll
      for (int mi = 0; mi < 4; ++mi)
#pragma unroll
        for (int ni = 0; ni < 4; ++ni)
          acc[mi][ni] = __builtin_amdgcn_mfma_f32_16x16x32_bf16(af[mi], bfr[ni], acc[mi][ni], 0, 0, 0);
    }
    __syncthreads();
  }
  const float* bias = b0;
  unsigned short* outb = o0;
  int nbase = n0, ostride = N;
  if (split) {
    int seg = n0 >> 9;
    if (seg == 1) { bias = b1; outb = o1; }
    else if (seg == 2) { bias = b2; outb = o2; }
    nbase = n0 & 511; ostride = 512;
  }
  int r0 = hi * 4;
#pragma unroll
  for (int ni = 0; ni < 4; ++ni) {
    int col = nbase + wn * 64 + ni * 16 + c16;
    float bv = bias[col];
#pragma unroll
    for (int mi = 0; mi < 4; ++mi) {
      int rowb = m0 + wm * 64 + mi * 16 + r0;
#pragma unroll
      for (int r = 0; r < 4; ++r) {
        float v = acc[mi][ni][r] + bv;
        if (relu) v = fmaxf(v, 0.0f);
        outb[(size_t)(rowb + r) * ostride + col] = f2bf(v);
      }
    }
  }
}

// ------------- fused GEMM (BM=64 x BN=512 full-row) + bias + residual + LayerNorm -------------
// 512 threads = 8 waves (2m x 4n), per-wave 32x128, grid = M/64 = 256 blocks
__global__ __launch_bounds__(512) void gemmln_kernel(
    const unsigned short* __restrict__ A, const unsigned short* __restrict__ Bt,
    const float* __restrict__ bias, const float* __restrict__ resid,
    const float* __restrict__ g, const float* __restrict__ bvec,
    float* __restrict__ Yf, unsigned short* __restrict__ Yb, int K) {
  __shared__ unsigned short As[64 * 32];
  __shared__ unsigned short Bs[512 * 32];
  __shared__ float redS[4][64];
  __shared__ float redQ[4][64];
  int tid = threadIdx.x, lane = tid & 63, wid = tid >> 6;
  int wm = wid >> 2, wn = wid & 3;
  int m0 = blockIdx.x * 64;
  f32x4 acc[2][8];
#pragma unroll
  for (int mi = 0; mi < 2; ++mi)
#pragma unroll
    for (int ni = 0; ni < 8; ++ni) acc[mi][ni] = (f32x4)0.0f;

  int srow = lane >> 2, scol = (lane & 3) * 8;
  int c16 = lane & 15, hi = lane >> 4, r0 = hi * 4;
  int koff = hi * 8;
  int nk = K >> 5;
  for (int kt = 0; kt < nk; ++kt) {
    int k0 = kt * 32;
#pragma unroll
    for (int i = 0; i < 4; ++i) {
      int c = wid * 4 + i;   // 32 B-chunks of 1KB
      gload_lds16(Bt + (size_t)(c * 16 + srow) * K + k0 + scol, (char*)Bs + c * 1024);
    }
    if (wid < 4)
      gload_lds16(A + (size_t)(m0 + wid * 16 + srow) * K + k0 + scol, (char*)As + wid * 1024);
    __syncthreads();
    bf16x8 af[2], bfr[8];
#pragma unroll
    for (int mi = 0; mi < 2; ++mi) af[mi] = *(const bf16x8*)&As[(wm * 32 + mi * 16 + c16) * 32 + koff];
#pragma unroll
    for (int ni = 0; ni < 8; ++ni) bfr[ni] = *(const bf16x8*)&Bs[(wn * 128 + ni * 16 + c16) * 32 + koff];
#pragma unroll
    for (int mi = 0; mi < 2; ++mi)
#pragma unroll
      for (int ni = 0; ni < 8; ++ni)
        acc[mi][ni] = __builtin_amdgcn_mfma_f32_16x16x32_bf16(af[mi], bfr[ni], acc[mi][ni], 0, 0, 0);
    __syncthreads();
  }

  // v = acc + bias + resid, held in acc
#pragma unroll
  for (int ni = 0; ni < 8; ++ni) {
    int col = wn * 128 + ni * 16 + c16;
    float bv = bias[col];
#pragma unroll
    for (int mi = 0; mi < 2; ++mi) {
      int rowb = m0 + wm * 32 + mi * 16 + r0;
#pragma unroll
      for (int r = 0; r < 4; ++r)
        acc[mi][ni][r] += bv + resid[(size_t)(rowb + r) * 512 + col];
    }
  }
  // pass 1: row sums
  float s_[2][4];
#pragma unroll
  for (int mi = 0; mi < 2; ++mi)
#pragma unroll
    for (int r = 0; r < 4; ++r) {
      float s = 0.0f;
#pragma unroll
      for (int ni = 0; ni < 8; ++ni) s += acc[mi][ni][r];
#pragma unroll
      for (int m = 1; m < 16; m <<= 1) s += __shfl_xor(s, m);
      s_[mi][r] = s;
    }
  if (c16 == 0) {
#pragma unroll
    for (int mi = 0; mi < 2; ++mi)
#pragma unroll
      for (int r = 0; r < 4; ++r) redS[wn][wm * 32 + mi * 16 + r0 + r] = s_[mi][r];
  }
  __syncthreads();
  float mean_[2][4];
#pragma unroll
  for (int mi = 0; mi < 2; ++mi)
#pragma unroll
    for (int r = 0; r < 4; ++r) {
      int rl = wm * 32 + mi * 16 + r0 + r;
      mean_[mi][r] = (redS[0][rl] + redS[1][rl] + redS[2][rl] + redS[3][rl]) * (1.0f / 512.0f);
    }
  // pass 2: centered sq sums
#pragma unroll
  for (int mi = 0; mi < 2; ++mi)
#pragma unroll
    for (int r = 0; r < 4; ++r) {
      float ss = 0.0f;
#pragma unroll
      for (int ni = 0; ni < 8; ++ni) {
        float d = acc[mi][ni][r] - mean_[mi][r];
        ss += d * d;
      }
#pragma unroll
      for (int m = 1; m < 16; m <<= 1) ss += __shfl_xor(ss, m);
      s_[mi][r] = ss;
    }
  if (c16 == 0) {
#pragma unroll
    for (int mi = 0; mi < 2; ++mi)
#pragma unroll
      for (int r = 0; r < 4; ++r) redQ[wn][wm * 32 + mi * 16 + r0 + r] = s_[mi][r];
  }
  __syncthreads();
#pragma unroll
  for (int mi = 0; mi < 2; ++mi)
#pragma unroll
    for (int r = 0; r < 4; ++r) {
      int rl = wm * 32 + mi * 16 + r0 + r;
      float var = (redQ[0][rl] + redQ[1][rl] + redQ[2][rl] + redQ[3][rl]) * (1.0f / 512.0f);
      s_[mi][r] = rsqrtf(var + 1e-5f);   // reuse as rstd
    }
#pragma unroll
  for (int ni = 0; ni < 8; ++ni) {
    int col = wn * 128 + ni * 16 + c16;
    float gg = g[col], bb = bvec[col];
#pragma unroll
    for (int mi = 0; mi < 2; ++mi) {
      int rowb = m0 + wm * 32 + mi * 16 + r0;
#pragma unroll
      for (int r = 0; r < 4; ++r) {
        float y = (acc[mi][ni][r] - mean_[mi][r]) * s_[mi][r] * gg + bb;
        size_t o = (size_t)(rowb + r) * 512 + col;
        Yf[o] = y;
        Yb[o] = f2bf(y);
      }
    }
  }
}

// ------------- flash attention over 256 groups of [512, 64], KVBLK=64, Q in regs -------------
#define KP2 72   // K LDS row stride
#define VP2 68   // V^T LDS row stride
#define PP2 68   // P LDS row stride
__global__ __launch_bounds__(256) void attn_kernel(
    const unsigned short* __restrict__ Q, const unsigned short* __restrict__ Kb,
    const unsigned short* __restrict__ Vb, unsigned short* __restrict__ Ctx) {
  __shared__ unsigned short Kl[64 * KP2];
  __shared__ unsigned short Vt[64 * VP2];
  __shared__ unsigned short Pl[4][32 * PP2];
  int g = blockIdx.y;
  int q0 = blockIdx.x * 128;
  const unsigned short* Qg = Q + ((size_t)g * 512 + q0) * 64;
  const unsigned short* Kg = Kb + (size_t)g * 512 * 64;
  const unsigned short* Vg = Vb + (size_t)g * 512 * 64;
  int tid = threadIdx.x, lane = tid & 63, wid = tid >> 6;
  int c16 = lane & 15, hi = lane >> 4, r0 = hi * 4;
  int wq0 = wid * 32;
  const float sc2 = 0.125f * 1.44269504f;   // scale * log2(e)

  // Q fragments in registers
  bf16x8 qf[2][2];
#pragma unroll
  for (int mi = 0; mi < 2; ++mi)
#pragma unroll
    for (int ks = 0; ks < 2; ++ks)
      qf[mi][ks] = *(const bf16x8*)(Qg + (size_t)(wq0 + mi * 16 + c16) * 64 + ks * 32 + hi * 8);

  float mr[2][4], ls[2][4];
  f32x4 cacc[2][4];
#pragma unroll
  for (int mi = 0; mi < 2; ++mi)
#pragma unroll
    for (int r = 0; r < 4; ++r) { mr[mi][r] = -1e30f; ls[mi][r] = 0.0f; }
#pragma unroll
  for (int mi = 0; mi < 2; ++mi)
#pragma unroll
    for (int nd = 0; nd < 4; ++nd) cacc[mi][nd] = (f32x4)0.0f;

  for (int kt = 0; kt < 8; ++kt) {
    __syncthreads();   // previous iter's Kl/Vt reads complete
#pragma unroll
    for (int i = 0; i < 2; ++i) {
      int row = (tid >> 3) + i * 32, oc = (tid & 7) * 8;
      bf16x8 kv = *(const bf16x8*)(Kg + (size_t)(kt * 64 + row) * 64 + oc);
      *(bf16x8*)&Kl[row * KP2 + oc] = kv;
      bf16x8 vv = *(const bf16x8*)(Vg + (size_t)(kt * 64 + row) * 64 + oc);
#pragma unroll
      for (int j = 0; j < 8; ++j) Vt[(oc + j) * VP2 + row] = (unsigned short)vv[j];
    }
    __syncthreads();   // staged tiles visible

    // QK^T: [32 q] x [64 j]
    f32x4 sacc[2][4];
#pragma unroll
    for (int mi = 0; mi < 2; ++mi)
#pragma unroll
      for (int nj = 0; nj < 4; ++nj) sacc[mi][nj] = (f32x4)0.0f;
#pragma unroll
    for (int ks = 0; ks < 2; ++ks) {
      bf16x8 kf[4];
#pragma unroll
      for (int nj = 0; nj < 4; ++nj)
        kf[nj] = *(const bf16x8*)&Kl[(nj * 16 + c16) * KP2 + ks * 32 + hi * 8];
#pragma unroll
      for (int mi = 0; mi < 2; ++mi)
#pragma unroll
        for (int nj = 0; nj < 4; ++nj)
          sacc[mi][nj] = __builtin_amdgcn_mfma_f32_16x16x32_bf16(qf[mi][ks], kf[nj], sacc[mi][nj], 0, 0, 0);
    }

    // online softmax in exp2 domain
#pragma unroll
    for (int mi = 0; mi < 2; ++mi) {
      float tmax[4];
#pragma unroll
      for (int r = 0; r < 4; ++r) {
        float t = fmaxf(fmaxf(sacc[mi][0][r], sacc[mi][1][r]), fmaxf(sacc[mi][2][r], sacc[mi][3][r]));
        tmax[r] = t * sc2;
      }
#pragma unroll
      for (int m = 1; m < 16; m <<= 1)
#pragma unroll
        for (int r = 0; r < 4; ++r) tmax[r] = fmaxf(tmax[r], __shfl_xor(tmax[r], m));
#pragma unroll
      for (int r = 0; r < 4; ++r) {
        float mnew = fmaxf(mr[mi][r], tmax[r]);
        float alpha = exp2f(mr[mi][r] - mnew);
        mr[mi][r] = mnew;
        ls[mi][r] *= alpha;
#pragma unroll
        for (int nd = 0; nd < 4; ++nd) cacc[mi][nd][r] *= alpha;
      }
      float rsum[4] = {0.f, 0.f, 0.f, 0.f};
#pragma unroll
      for (int nj = 0; nj < 4; ++nj)
#pragma unroll
        for (int r = 0; r < 4; ++r) {
          float p = exp2f(sacc[mi][nj][r] * sc2 - mr[mi][r]);
          rsum[r] += p;
          Pl[wid][(mi * 16 + r0 + r) * PP2 + nj * 16 + c16] = f2bf(p);
        }
#pragma unroll
      for (int m = 1; m < 16; m <<= 1)
#pragma unroll
        for (int r = 0; r < 4; ++r) rsum[r] += __shfl_xor(rsum[r], m);
#pragma unroll
      for (int r = 0; r < 4; ++r) ls[mi][r] += rsum[r];
    }

    // PV: ctx[32 q][64 dh] += P[32 q][64 j] @ V[64 j][64 dh]
#pragma unroll
    for (int ks = 0; ks < 2; ++ks) {
      bf16x8 vf[4];
#pragma unroll
      for (int nd = 0; nd < 4; ++nd)
        vf[nd] = *(const bf16x8*)&Vt[(nd * 16 + c16) * VP2 + ks * 32 + hi * 8];
#pragma unroll
      for (int mi = 0; mi < 2; ++mi) {
        bf16x8 pf = *(const bf16x8*)&Pl[wid][(mi * 16 + c16) * PP2 + ks * 32 + hi * 8];
#pragma unroll
        for (int nd = 0; nd < 4; ++nd)
          cacc[mi][nd] = __builtin_amdgcn_mfma_f32_16x16x32_bf16(pf, vf[nd], cacc[mi][nd], 0, 0, 0);
      }
    }
  }

#pragma unroll
  for (int mi = 0; mi < 2; ++mi)
#pragma unroll
    for (int nd = 0; nd < 4; ++nd)
#pragma unroll
      for (int r = 0; r < 4; ++r) {
        float v = cacc[mi][nd][r] / ls[mi][r];
        int row = q0 + wq0 + mi * 16 + r0 + r;
        int col = nd * 16 + c16;
        Ctx[((size_t)g * 512 + row) * 64 + col] = f2bf(v);
      }
}

// ------------- final FC: out[32][1000] = act[32][262144] @ Wfc + bfc (split-K) -------------
#define KCH 1024
__global__ __launch_bounds__(256) void fc_part_kernel(const float* __restrict__ act,
                                                      const float* __restrict__ Wfc,
                                                      float* __restrict__ part) {
  __shared__ float al[32][256];
  int o = blockIdx.x * 256 + threadIdx.x;
  int kc = blockIdx.y;
  size_t k0 = (size_t)kc * KCH;
  float acc[32];
#pragma unroll
  for (int bb = 0; bb < 32; ++bb) acc[bb] = 0.0f;
  for (int sub = 0; sub < KCH / 256; ++sub) {
    __syncthreads();
    for (int i = threadIdx.x; i < 32 * 256; i += 256) {
      int bb = i >> 8, kk = i & 255;
      al[bb][kk] = act[(size_t)bb * 262144 + k0 + sub * 256 + kk];
    }
    __syncthreads();
    if (o < O_) {
      const float* wp = Wfc + (k0 + sub * 256) * O_ + o;
      for (int kk = 0; kk < 256; ++kk) {
        float w = wp[(size_t)kk * O_];
#pragma unroll
        for (int bb = 0; bb < 32; ++bb) acc[bb] = fmaf(al[bb][kk], w, acc[bb]);
      }
    }
  }
  if (o < O_) {
#pragma unroll
    for (int bb = 0; bb < 32; ++bb) part[((size_t)kc * 32 + bb) * O_ + o] = acc[bb];
  }
}

__global__ void fc_reduce_kernel(const float* __restrict__ part, const float* __restrict__ bfc,
                                 float* __restrict__ out) {
  int o = blockIdx.x * 256 + threadIdx.x;
  int b = blockIdx.y;
  if (o >= O_) return;
  float s = bfc[o];
  for (int c = 0; c < 256; ++c) s += part[((size_t)c * 32 + b) * O_ + o];
  out[(size_t)b * O_ + o] = s;
}

extern "C" void kernel_launch(void* const* d_in, const int* in_sizes, int n_in,
                              void* d_out, int out_size, void* d_ws, size_t ws_size,
                              hipStream_t stream) {
  const int*   x   = (const int*)d_in[0];
  const float* emb = (const float*)d_in[2];
  const float* Wq  = (const float*)d_in[3];
  const float* bq  = (const float*)d_in[4];
  const float* Wk  = (const float*)d_in[5];
  const float* bk  = (const float*)d_in[6];
  const float* Wv  = (const float*)d_in[7];
  const float* bv  = (const float*)d_in[8];
  const float* Wo  = (const float*)d_in[9];
  const float* bo  = (const float*)d_in[10];
  const float* g1  = (const float*)d_in[11];
  const float* bn1 = (const float*)d_in[12];
  const float* W1  = (const float*)d_in[13];
  const float* bf1 = (const float*)d_in[14];
  const float* W2  = (const float*)d_in[15];
  const float* bf2 = (const float*)d_in[16];
  const float* g2  = (const float*)d_in[17];
  const float* bn2 = (const float*)d_in[18];
  const float* Wfc = (const float*)d_in[19];
  const float* bfc = (const float*)d_in[20];
  float* out = (float*)d_out;

  char* ws = (char*)d_ws;
  size_t off = 0;
  auto take = [&](size_t bytes) { char* p = ws + off; off += (bytes + 255) & ~(size_t)255; return p; };
  float*          pe   = (float*)take((size_t)512 * 512 * 4);
  unsigned short* wqkv = (unsigned short*)take((size_t)L_ * 1536 * 512 * 2);
  unsigned short* wot  = (unsigned short*)take((size_t)L_ * 512 * 512 * 2);
  unsigned short* w1t  = (unsigned short*)take((size_t)L_ * 2048 * 512 * 2);
  unsigned short* w2t  = (unsigned short*)take((size_t)L_ * 512 * 2048 * 2);
  float*          xf   = (float*)take((size_t)M_ * 512 * 4);
  unsigned short* xb   = (unsigned short*)take((size_t)M_ * 512 * 2);
  unsigned short* qb   = (unsigned short*)take((size_t)M_ * 512 * 2);
  unsigned short* kb   = (unsigned short*)take((size_t)M_ * 512 * 2);
  unsigned short* vb   = (unsigned short*)take((size_t)M_ * 512 * 2);
  unsigned short* cxb  = (unsigned short*)take((size_t)M_ * 512 * 2);
  float*          hf   = (float*)take((size_t)M_ * 512 * 4);
  unsigned short* hb   = (unsigned short*)take((size_t)M_ * 512 * 2);
  unsigned short* f1b  = qb;          // alias: q/k/v/ctx region (67 MB) free during FFN
  float*          part = (float*)qb;  // alias: free after last layer

  pe_kernel<<<1024, 256, 0, stream>>>(pe);
  wconv_kernel<<<dim3(16, 16, L_), 256, 0, stream>>>(Wq, wqkv,          512, 512,  (size_t)1536 * 512);
  wconv_kernel<<<dim3(16, 16, L_), 256, 0, stream>>>(Wk, wqkv + 262144, 512, 512,  (size_t)1536 * 512);
  wconv_kernel<<<dim3(16, 16, L_), 256, 0, stream>>>(Wv, wqkv + 524288, 512, 512,  (size_t)1536 * 512);
  wconv_kernel<<<dim3(16, 16, L_), 256, 0, stream>>>(Wo, wot,           512, 512,  (size_t)512 * 512);
  wconv_kernel<<<dim3(16, 64, L_), 256, 0, stream>>>(W1, w1t,           512, 2048, (size_t)2048 * 512);
  wconv_kernel<<<dim3(64, 16, L_), 256, 0, stream>>>(W2, w2t,           2048, 512, (size_t)512 * 2048);
  embed_kernel<<<M_, 128, 0, stream>>>(x, emb, pe, xf, xb);

  for (int l = 0; l < L_; ++l) {
    gemm_kernel<<<dim3(12, 128), 256, 0, stream>>>(
        xb, wqkv + (size_t)l * 1536 * 512,
        bq + l * 512, bk + l * 512, bv + l * 512,
        qb, kb, vb, 512, 1536, 0, 1);
    attn_kernel<<<dim3(4, G_), 256, 0, stream>>>(qb, kb, vb, cxb);
    gemmln_kernel<<<256, 512, 0, stream>>>(
        cxb, wot + (size_t)l * 512 * 512, bo + l * 512, xf,
        g1 + l * 512, bn1 + l * 512, hf, hb, 512);
    gemm_kernel<<<dim3(16, 128), 256, 0, stream>>>(
        hb, w1t + (size_t)l * 2048 * 512,
        bf1 + l * 2048, nullptr, nullptr,
        f1b, nullptr, nullptr, 512, 2048, 1, 0);
    gemmln_kernel<<<256, 512, 0, stream>>>(
        f1b, w2t + (size_t)l * 512 * 2048, bf2 + l * 512, hf,
        g2 + l * 512, bn2 + l * 512, xf, xb, 2048);
  }

  fc_part_kernel<<<dim3(4, 256), 256, 0, stream>>>(xf, Wfc, part);
  fc_reduce_kernel<<<dim3(4, 32), 256, 0, stream>>>(part, bfc, out);
}

// Round 4
// 2322.520 us; speedup vs baseline: 1.2642x; 1.1008x over previous
//
#include <hip/hip_runtime.h>
#include <cstdint>
#include <cstddef>

#define S_  512
#define B_  32
#define D_  512
#define FF_ 2048
#define L_  6
#define O_  1000
#define M_  (B_*S_)     // 16384 rows of activations
#define G_  256         // attention groups (buggy reshape semantics)
#define DH_ 64

typedef __attribute__((ext_vector_type(8))) short bf16x8;
typedef __attribute__((ext_vector_type(4))) float f32x4;
typedef __attribute__((ext_vector_type(16))) float f32x16;

__device__ __forceinline__ unsigned short f2bf(float f) {
  unsigned int u = __builtin_bit_cast(unsigned int, f);
  u = (u + 0x7fffu + ((u >> 16) & 1u)) >> 16;
  return (unsigned short)u;
}
__device__ __forceinline__ float bf2f(unsigned short u) {
  return __builtin_bit_cast(float, (unsigned int)u << 16);
}
__device__ __forceinline__ unsigned int pkbf(float a, float b) {
  return (unsigned int)f2bf(a) | ((unsigned int)f2bf(b) << 16);
}
__device__ __forceinline__ void gload_lds16(const void* g, void* l) {
  __builtin_amdgcn_global_load_lds(
      (const __attribute__((address_space(1))) unsigned int*)g,
      (__attribute__((address_space(3))) unsigned int*)l, 16, 0, 0);
}

// ---------------- positional encoding table [512][512] f32 ----------------
__global__ void pe_kernel(float* __restrict__ pe) {
  int i = blockIdx.x * 256 + threadIdx.x;
  int s = i >> 9, d = i & 511;
  double de = (double)(d & ~1);
  double ang = (double)s * exp(de * (-9.210340371976184 / 512.0));
  pe[i] = (d & 1) ? (float)cos(ang) : (float)sin(ang);
}

// ------------- transpose-convert W [z][K][N] f32 -> Wt [z-stride ozs][N][K] bf16 -------------
__global__ void wconv_kernel(const float* __restrict__ W, unsigned short* __restrict__ Wt,
                             int K, int N, size_t ozs) {
  __shared__ float tile[32][33];
  const float* Wl = W + (size_t)blockIdx.z * K * N;
  unsigned short* Wtl = Wt + (size_t)blockIdx.z * ozs;
  int k0 = blockIdx.x * 32, n0 = blockIdx.y * 32;
  int c = threadIdx.x & 31, rb = threadIdx.x >> 5;
#pragma unroll
  for (int i = 0; i < 4; ++i) {
    int r = rb + i * 8;
    tile[r][c] = Wl[(size_t)(k0 + r) * N + n0 + c];
  }
  __syncthreads();
#pragma unroll
  for (int i = 0; i < 4; ++i) {
    int r = rb + i * 8;
    Wtl[(size_t)(n0 + r) * K + k0 + c] = f2bf(tile[c][r]);
  }
}

// ------------- embedding + PE -------------
__global__ void embed_kernel(const int* __restrict__ x, const float* __restrict__ emb,
                             const float* __restrict__ pe,
                             float* __restrict__ xf, unsigned short* __restrict__ xb) {
  int bi = blockIdx.x;            // s*B + b
  int s = bi / B_, b = bi % B_;
  int tok = x[s * B_ + b];
  int d = threadIdx.x * 4;
  float4 e = *(const float4*)(emb + (size_t)tok * D_ + d);
  float4 p = *(const float4*)(pe + (size_t)s * D_ + d);
  float v0 = e.x + p.x, v1 = e.y + p.y, v2 = e.z + p.z, v3 = e.w + p.w;
  size_t o = ((size_t)b * S_ + s) * D_ + d;
  *(float4*)(xf + o) = make_float4(v0, v1, v2, v3);
  ushort4 u; u.x = f2bf(v0); u.y = f2bf(v1); u.z = f2bf(v2); u.w = f2bf(v3);
  *(ushort4*)(xb + o) = u;
}

// ------------- bf16 MFMA GEMM, 128x128 tile, BK=64, swapped-operand epilogue -------------
__global__ __launch_bounds__(256) void gemm_kernel(
    const unsigned short* __restrict__ A, const unsigned short* __restrict__ Bt,
    const float* __restrict__ b0, const float* __restrict__ b1, const float* __restrict__ b2,
    unsigned short* __restrict__ o0, unsigned short* __restrict__ o1, unsigned short* __restrict__ o2,
    int K, int N, int relu, int split) {
  __shared__ unsigned short As[2 * 128 * 32];
  __shared__ unsigned short Bs[2 * 128 * 32];
  int tid = threadIdx.x, lane = tid & 63, wid = tid >> 6;
  int m0 = blockIdx.y * 128, n0 = blockIdx.x * 128;
  int wm = wid >> 1, wn = wid & 1;
  f32x4 acc[4][4];
#pragma unroll
  for (int mi = 0; mi < 4; ++mi)
#pragma unroll
    for (int ni = 0; ni < 4; ++ni) acc[mi][ni] = (f32x4)0.0f;

  int srow = lane >> 2, scol = (lane & 3) * 8;
  const unsigned short* Abase = A + (size_t)m0 * K;
  const unsigned short* Bbase = Bt + (size_t)n0 * K;
  int c16 = lane & 15, hi = lane >> 4;
  int koff = hi * 8;
  int arow = wm * 64 + c16, brow = wn * 64 + c16;
  int nk = K >> 6;
  for (int kt = 0; kt < nk; ++kt) {
    int k0 = kt * 64;
#pragma unroll
    for (int i = 0; i < 4; ++i) {
      int c = wid * 4 + i;
      int ks = c >> 3;
      int rl = (c & 7) * 16 + srow;
      int cc = k0 + ks * 32 + scol;
      gload_lds16(Abase + (size_t)rl * K + cc, (char*)As + c * 1024);
      gload_lds16(Bbase + (size_t)rl * K + cc, (char*)Bs + c * 1024);
    }
    __syncthreads();
#pragma unroll
    for (int ks = 0; ks < 2; ++ks) {
      bf16x8 af[4], bfr[4];
#pragma unroll
      for (int mi = 0; mi < 4; ++mi) af[mi] = *(const bf16x8*)&As[ks * 4096 + (arow + mi * 16) * 32 + koff];
#pragma unroll
      for (int ni = 0; ni < 4; ++ni) bfr[ni] = *(const bf16x8*)&Bs[ks * 4096 + (brow + ni * 16) * 32 + koff];
#pragma unroll
      for (int mi = 0; mi < 4; ++mi)
#pragma unroll
        for (int ni = 0; ni < 4; ++ni)
          acc[mi][ni] = __builtin_amdgcn_mfma_f32_16x16x32_bf16(bfr[ni], af[mi], acc[mi][ni], 0, 0, 0);
    }
    __syncthreads();
  }
  const float* bias = b0;
  unsigned short* outb = o0;
  int nbase = n0, ostride = N;
  if (split) {
    int seg = n0 >> 9;
    if (seg == 1) { bias = b1; outb = o1; }
    else if (seg == 2) { bias = b2; outb = o2; }
    nbase = n0 & 511; ostride = 512;
  }
  // swapped layout: lane holds row = ...+c16, cols = ...+hi*4+{0..3}
#pragma unroll
  for (int ni = 0; ni < 4; ++ni) {
    int colb = nbase + wn * 64 + ni * 16 + hi * 4;
    float4 bv = *(const float4*)(bias + colb);
#pragma unroll
    for (int mi = 0; mi < 4; ++mi) {
      int row = m0 + wm * 64 + mi * 16 + c16;
      float v0 = acc[mi][ni][0] + bv.x;
      float v1 = acc[mi][ni][1] + bv.y;
      float v2 = acc[mi][ni][2] + bv.z;
      float v3 = acc[mi][ni][3] + bv.w;
      if (relu) { v0 = fmaxf(v0, 0.f); v1 = fmaxf(v1, 0.f); v2 = fmaxf(v2, 0.f); v3 = fmaxf(v3, 0.f); }
      *(uint2*)(outb + (size_t)row * ostride + colb) = make_uint2(pkbf(v0, v1), pkbf(v2, v3));
    }
  }
}

// ------------- fused GEMM (BM=32 x BN=512) + bias + residual + LayerNorm -------------
// 512 threads = 8 waves, each wave owns 64 cols; grid = M/32 = 512 blocks (2 blocks/CU)
__global__ __launch_bounds__(512) void gemmln_kernel(
    const unsigned short* __restrict__ A, const unsigned short* __restrict__ Bt,
    const float* __restrict__ bias, const float* __restrict__ resid,
    const float* __restrict__ g, const float* __restrict__ bvec,
    float* __restrict__ Yf, unsigned short* __restrict__ Yb, int K) {
  __shared__ unsigned short As[32 * 32];
  __shared__ unsigned short Bs[512 * 32];
  __shared__ float redS[8][32];
  __shared__ float redQ[8][32];
  int tid = threadIdx.x, lane = tid & 63, wid = tid >> 6;
  int wn = wid;                       // 0..7, 64-col slice
  int m0 = blockIdx.x * 32;
  f32x4 acc[2][4];
#pragma unroll
  for (int mi = 0; mi < 2; ++mi)
#pragma unroll
    for (int ni = 0; ni < 4; ++ni) acc[mi][ni] = (f32x4)0.0f;

  int srow = lane >> 2, scol = (lane & 3) * 8;
  int c16 = lane & 15, hi = lane >> 4;
  int koff = hi * 8;
  int nk = K >> 5;
  for (int kt = 0; kt < nk; ++kt) {
    int k0 = kt * 32;
#pragma unroll
    for (int i = 0; i < 4; ++i) {
      int c = wid * 4 + i;   // 32 chunks of 1KB covering Bs[512][32]
      gload_lds16(Bt + (size_t)(c * 16 + srow) * K + k0 + scol, (char*)Bs + c * 1024);
    }
    if (wid < 2)
      gload_lds16(A + (size_t)(m0 + wid * 16 + srow) * K + k0 + scol, (char*)As + wid * 1024);
    __syncthreads();
    bf16x8 af[2], bfr[4];
#pragma unroll
    for (int mi = 0; mi < 2; ++mi) af[mi] = *(const bf16x8*)&As[(mi * 16 + c16) * 32 + koff];
#pragma unroll
    for (int ni = 0; ni < 4; ++ni) bfr[ni] = *(const bf16x8*)&Bs[(wn * 64 + ni * 16 + c16) * 32 + koff];
#pragma unroll
    for (int mi = 0; mi < 2; ++mi)
#pragma unroll
      for (int ni = 0; ni < 4; ++ni)
        acc[mi][ni] = __builtin_amdgcn_mfma_f32_16x16x32_bf16(bfr[ni], af[mi], acc[mi][ni], 0, 0, 0);
    __syncthreads();
  }

  // acc += bias + resid (lane: row = m0+mi*16+c16, cols = wn*64+ni*16+hi*4+{0..3})
#pragma unroll
  for (int ni = 0; ni < 4; ++ni) {
    int colb = wn * 64 + ni * 16 + hi * 4;
    float4 bv = *(const float4*)(bias + colb);
#pragma unroll
    for (int mi = 0; mi < 2; ++mi) {
      int row = m0 + mi * 16 + c16;
      float4 rv = *(const float4*)(resid + (size_t)row * 512 + colb);
      acc[mi][ni][0] += bv.x + rv.x;
      acc[mi][ni][1] += bv.y + rv.y;
      acc[mi][ni][2] += bv.z + rv.z;
      acc[mi][ni][3] += bv.w + rv.w;
    }
  }
  // row sums (in-lane 16 + cross hi/wave)
  float mean_[2], rstd_[2];
#pragma unroll
  for (int mi = 0; mi < 2; ++mi) {
    float s = 0.0f;
#pragma unroll
    for (int ni = 0; ni < 4; ++ni)
#pragma unroll
      for (int r = 0; r < 4; ++r) s += acc[mi][ni][r];
    s += __shfl_xor(s, 16);
    s += __shfl_xor(s, 32);
    if (lane < 16) redS[wn][mi * 16 + lane] = s;
  }
  __syncthreads();
#pragma unroll
  for (int mi = 0; mi < 2; ++mi) {
    int rl = mi * 16 + c16;
    float s = 0.0f;
#pragma unroll
    for (int w = 0; w < 8; ++w) s += redS[w][rl];
    mean_[mi] = s * (1.0f / 512.0f);
  }
  // centered square sums
#pragma unroll
  for (int mi = 0; mi < 2; ++mi) {
    float ss = 0.0f;
#pragma unroll
    for (int ni = 0; ni < 4; ++ni)
#pragma unroll
      for (int r = 0; r < 4; ++r) {
        float d = acc[mi][ni][r] - mean_[mi];
        ss += d * d;
      }
    ss += __shfl_xor(ss, 16);
    ss += __shfl_xor(ss, 32);
    if (lane < 16) redQ[wn][mi * 16 + lane] = ss;
  }
  __syncthreads();
#pragma unroll
  for (int mi = 0; mi < 2; ++mi) {
    int rl = mi * 16 + c16;
    float ss = 0.0f;
#pragma unroll
    for (int w = 0; w < 8; ++w) ss += redQ[w][rl];
    rstd_[mi] = rsqrtf(ss * (1.0f / 512.0f) + 1e-5f);
  }
  // normalize + write (float4 + packed bf16x4)
#pragma unroll
  for (int mi = 0; mi < 2; ++mi) {
    float mu = mean_[mi], rs = rstd_[mi];
    int row = m0 + mi * 16 + c16;
#pragma unroll
    for (int ni = 0; ni < 4; ++ni) {
      int colb = wn * 64 + ni * 16 + hi * 4;
      float4 gg = *(const float4*)(g + colb);
      float4 bb = *(const float4*)(bvec + colb);
      float y0 = (acc[mi][ni][0] - mu) * rs * gg.x + bb.x;
      float y1 = (acc[mi][ni][1] - mu) * rs * gg.y + bb.y;
      float y2 = (acc[mi][ni][2] - mu) * rs * gg.z + bb.z;
      float y3 = (acc[mi][ni][3] - mu) * rs * gg.w + bb.w;
      size_t o = (size_t)row * 512 + colb;
      *(float4*)(Yf + o) = make_float4(y0, y1, y2, y3);
      *(uint2*)(Yb + o) = make_uint2(pkbf(y0, y1), pkbf(y2, y3));
    }
  }
}

// ------------- flash attention, 32x32 swapped-QK^T, in-register softmax -------------
// grid (4, 256): 4 q-blocks of 128, 256 groups. 4 waves, wave owns 32 q rows.
__global__ __launch_bounds__(256) void attn_kernel(
    const unsigned short* __restrict__ Q, const unsigned short* __restrict__ Kb,
    const unsigned short* __restrict__ Vb, unsigned short* __restrict__ Ctx) {
  __shared__ char KlB[8192];   // K tile [64 k][64 d] bf16, XOR-swizzled rows
  __shared__ char VtB[8192];   // V^T tile [64 d][64 k] bf16, XOR-swizzled rows
  int g = blockIdx.y;
  int q0 = blockIdx.x * 128;
  const unsigned short* Kg = Kb + (size_t)g * 512 * 64;
  const unsigned short* Vg = Vb + (size_t)g * 512 * 64;
  int tid = threadIdx.x, lane = tid & 63, wid = tid >> 6;
  int l31 = lane & 31, h = lane >> 5;
  bool lo = (lane < 32);
  int qrow = q0 + wid * 32 + l31;
  const float sc2 = 0.125f * 1.44269504f;

  // Q fragments (x scale) in regs: qf[c] = Q[qrow][16c + 8h + j] * sc2
  bf16x8 qf[4];
  {
    const unsigned short* qp = Q + ((size_t)g * 512 + qrow) * 64;
#pragma unroll
    for (int c = 0; c < 4; ++c) {
      bf16x8 raw = *(const bf16x8*)(qp + c * 16 + h * 8);
      union { unsigned int u[4]; bf16x8 v; } uu;
#pragma unroll
      for (int j = 0; j < 4; ++j)
        uu.u[j] = pkbf(bf2f((unsigned short)raw[2 * j]) * sc2,
                       bf2f((unsigned short)raw[2 * j + 1]) * sc2);
      qf[c] = uu.v;
    }
  }

  f32x16 c0 = (f32x16)0.0f, c1 = (f32x16)0.0f;   // O^T[d][q], d-halves
  float mr = -3.0e38f, ls = 0.0f;

  for (int kt = 0; kt < 8; ++kt) {
    __syncthreads();
    {
      int row = tid >> 2;
      size_t base = (size_t)(kt * 64 + row) * 64;
#pragma unroll
      for (int i = 0; i < 2; ++i) {
        int cb = ((tid & 3) + 4 * i) * 16;       // byte col within 128B row
        bf16x8 kv = *(const bf16x8*)(Kg + base + cb / 2);
        *(bf16x8*)(KlB + row * 128 + (cb ^ ((row & 7) << 4))) = kv;
        bf16x8 vv = *(const bf16x8*)(Vg + base + cb / 2);
#pragma unroll
        for (int j = 0; j < 8; ++j) {
          int d = cb / 2 + j;
          *(unsigned short*)(VtB + d * 128 + ((2 * row) ^ ((d & 7) << 4))) =
              (unsigned short)vv[j];
        }
      }
    }
    __syncthreads();

    // S^T[k][q] = K . Q^T : two 32-row sub-tiles, 4 d-chunks of 16
    f32x16 s0 = (f32x16)0.0f, s1 = (f32x16)0.0f;
#pragma unroll
    for (int c = 0; c < 4; ++c) {
      int cb = 32 * c + 16 * h;
      int sw = cb ^ ((l31 & 7) << 4);
      bf16x8 k0 = *(const bf16x8*)(KlB + l31 * 128 + sw);
      bf16x8 k1 = *(const bf16x8*)(KlB + (32 + l31) * 128 + sw);
      s0 = __builtin_amdgcn_mfma_f32_32x32x16_bf16(k0, qf[c], s0, 0, 0, 0);
      s1 = __builtin_amdgcn_mfma_f32_32x32x16_bf16(k1, qf[c], s1, 0, 0, 0);
    }

    // online softmax: lane holds 32 of 64 k-values for its q; partner lane^32 has the rest
    float pm = s0[0];
#pragma unroll
    for (int i = 1; i < 16; ++i) pm = fmaxf(pm, s0[i]);
#pragma unroll
    for (int i = 0; i < 16; ++i) pm = fmaxf(pm, s1[i]);
    pm = fmaxf(pm, __shfl_xor(pm, 32));
    float mnew = fmaxf(mr, pm);
    float alpha = exp2f(mr - mnew);
    mr = mnew;
    float p[32];
    float rs = 0.0f;
#pragma unroll
    for (int i = 0; i < 16; ++i) { p[i] = exp2f(s0[i] - mnew); rs += p[i]; }
#pragma unroll
    for (int i = 0; i < 16; ++i) { p[16 + i] = exp2f(s1[i] - mnew); rs += p[16 + i]; }
    float rso = __shfl_xor(rs, 32);
    ls = ls * alpha + rs + rso;
#pragma unroll
    for (int i = 0; i < 16; ++i) { c0[i] *= alpha; c1[i] *= alpha; }

    // P -> bf16 A/B-frags: pa[kcg] holds P[q=lane&31][k = 16*kcg + 8h + j]
    union { unsigned int u[4]; bf16x8 v; } pa[4];
#pragma unroll
    for (int t = 0; t < 2; ++t) {
#pragma unroll
      for (int u = 0; u < 2; ++u) {
#pragma unroll
        for (int pr = 0; pr < 2; ++pr) {
          const int b0i = t * 16 + 8 * u;
          unsigned int a  = pkbf(p[b0i + 2 * pr],     p[b0i + 2 * pr + 1]);
          unsigned int b  = pkbf(p[b0i + 4 + 2 * pr], p[b0i + 4 + 2 * pr + 1]);
          unsigned int sa = __shfl_xor(a, 32);
          unsigned int sb = __shfl_xor(b, 32);
          pa[t * 2 + u].u[pr]     = lo ? a  : sb;   // word pr   (k = 8h + 2pr..)
          pa[t * 2 + u].u[2 + pr] = lo ? sa : b;    // word pr+2 (k = 8h+4+2pr..)
        }
      }
    }

    // O^T[d][q] += V^T . P : 4 k-chunks of 16, two d-halves
#pragma unroll
    for (int kc = 0; kc < 4; ++kc) {
      int cb = 32 * kc + 16 * h;
      int sw = cb ^ ((l31 & 7) << 4);
      bf16x8 v0 = *(const bf16x8*)(VtB + l31 * 128 + sw);
      bf16x8 v1 = *(const bf16x8*)(VtB + (32 + l31) * 128 + sw);
      c0 = __builtin_amdgcn_mfma_f32_32x32x16_bf16(v0, pa[kc].v, c0, 0, 0, 0);
      c1 = __builtin_amdgcn_mfma_f32_32x32x16_bf16(v1, pa[kc].v, c1, 0, 0, 0);
    }
  }

  // epilogue: lane owns q = qrow; d = (reg&3) + 8*(reg>>2) + 4h + 32*dh
  float inv = 1.0f / ls;
  unsigned short* cp = Ctx + ((size_t)g * 512 + qrow) * 64;
#pragma unroll
  for (int dh = 0; dh < 2; ++dh) {
#pragma unroll
    for (int rq = 0; rq < 4; ++rq) {
      float e0 = (dh ? c1[rq * 4 + 0] : c0[rq * 4 + 0]) * inv;
      float e1 = (dh ? c1[rq * 4 + 1] : c0[rq * 4 + 1]) * inv;
      float e2 = (dh ? c1[rq * 4 + 2] : c0[rq * 4 + 2]) * inv;
      float e3 = (dh ? c1[rq * 4 + 3] : c0[rq * 4 + 3]) * inv;
      int d0 = dh * 32 + rq * 8 + h * 4;
      *(uint2*)(cp + d0) = make_uint2(pkbf(e0, e1), pkbf(e2, e3));
    }
  }
}

// ------------- final FC: out[32][1000] = act[32][262144] @ Wfc + bfc (split-K) -------------
#define KCH 1024
__global__ __launch_bounds__(256) void fc_part_kernel(const float* __restrict__ act,
                                                      const float* __restrict__ Wfc,
                                                      float* __restrict__ part) {
  __shared__ float al[32][256];
  int o = blockIdx.x * 256 + threadIdx.x;
  int kc = blockIdx.y;
  size_t k0 = (size_t)kc * KCH;
  float acc[32];
#pragma unroll
  for (int bb = 0; bb < 32; ++bb) acc[bb] = 0.0f;
  for (int sub = 0; sub < KCH / 256; ++sub) {
    __syncthreads();
    for (int i = threadIdx.x; i < 32 * 256; i += 256) {
      int bb = i >> 8, kk = i & 255;
      al[bb][kk] = act[(size_t)bb * 262144 + k0 + sub * 256 + kk];
    }
    __syncthreads();
    if (o < O_) {
      const float* wp = Wfc + (k0 + sub * 256) * O_ + o;
      for (int kk = 0; kk < 256; ++kk) {
        float w = wp[(size_t)kk * O_];
#pragma unroll
        for (int bb = 0; bb < 32; ++bb) acc[bb] = fmaf(al[bb][kk], w, acc[bb]);
      }
    }
  }
  if (o < O_) {
#pragma unroll
    for (int bb = 0; bb < 32; ++bb) part[((size_t)kc * 32 + bb) * O_ + o] = acc[bb];
  }
}

__global__ void fc_reduce_kernel(const float* __restrict__ part, const float* __restrict__ bfc,
                                 float* __restrict__ out) {
  int o = blockIdx.x * 256 + threadIdx.x;
  int b = blockIdx.y;
  if (o >= O_) return;
  float s = bfc[o];
  for (int c = 0; c < 256; ++c) s += part[((size_t)c * 32 + b) * O_ + o];
  out[(size_t)b * O_ + o] = s;
}

extern "C" void kernel_launch(void* const* d_in, const int* in_sizes, int n_in,
                              void* d_out, int out_size, void* d_ws, size_t ws_size,
                              hipStream_t stream) {
  const int*   x   = (const int*)d_in[0];
  const float* emb = (const float*)d_in[2];
  const float* Wq  = (const float*)d_in[3];
  const float* bq  = (const float*)d_in[4];
  const float* Wk  = (const float*)d_in[5];
  const float* bk  = (const float*)d_in[6];
  const float* Wv  = (const float*)d_in[7];
  const float* bv  = (const float*)d_in[8];
  const float* Wo  = (const float*)d_in[9];
  const float* bo  = (const float*)d_in[10];
  const float* g1  = (const float*)d_in[11];
  const float* bn1 = (const float*)d_in[12];
  const float* W1  = (const float*)d_in[13];
  const float* bf1 = (const float*)d_in[14];
  const float* W2  = (const float*)d_in[15];
  const float* bf2 = (const float*)d_in[16];
  const float* g2  = (const float*)d_in[17];
  const float* bn2 = (const float*)d_in[18];
  const float* Wfc = (const float*)d_in[19];
  const float* bfc = (const float*)d_in[20];
  float* out = (float*)d_out;

  char* ws = (char*)d_ws;
  size_t off = 0;
  auto take = [&](size_t bytes) { char* p = ws + off; off += (bytes + 255) & ~(size_t)255; return p; };
  float*          pe   = (float*)take((size_t)512 * 512 * 4);
  unsigned short* wqkv = (unsigned short*)take((size_t)L_ * 1536 * 512 * 2);
  unsigned short* wot  = (unsigned short*)take((size_t)L_ * 512 * 512 * 2);
  unsigned short* w1t  = (unsigned short*)take((size_t)L_ * 2048 * 512 * 2);
  unsigned short* w2t  = (unsigned short*)take((size_t)L_ * 512 * 2048 * 2);
  float*          xf   = (float*)take((size_t)M_ * 512 * 4);
  unsigned short* xb   = (unsigned short*)take((size_t)M_ * 512 * 2);
  unsigned short* qb   = (unsigned short*)take((size_t)M_ * 512 * 2);
  unsigned short* kb   = (unsigned short*)take((size_t)M_ * 512 * 2);
  unsigned short* vb   = (unsigned short*)take((size_t)M_ * 512 * 2);
  unsigned short* cxb  = (unsigned short*)take((size_t)M_ * 512 * 2);
  float*          hf   = (float*)take((size_t)M_ * 512 * 4);
  unsigned short* hb   = (unsigned short*)take((size_t)M_ * 512 * 2);
  unsigned short* f1b  = qb;          // alias: q/k/v region free during FFN
  float*          part = (float*)qb;  // alias: free after last layer

  pe_kernel<<<1024, 256, 0, stream>>>(pe);
  wconv_kernel<<<dim3(16, 16, L_), 256, 0, stream>>>(Wq, wqkv,          512, 512,  (size_t)1536 * 512);
  wconv_kernel<<<dim3(16, 16, L_), 256, 0, stream>>>(Wk, wqkv + 262144, 512, 512,  (size_t)1536 * 512);
  wconv_kernel<<<dim3(16, 16, L_), 256, 0, stream>>>(Wv, wqkv + 524288, 512, 512,  (size_t)1536 * 512);
  wconv_kernel<<<dim3(16, 16, L_), 256, 0, stream>>>(Wo, wot,           512, 512,  (size_t)512 * 512);
  wconv_kernel<<<dim3(16, 64, L_), 256, 0, stream>>>(W1, w1t,           512, 2048, (size_t)2048 * 512);
  wconv_kernel<<<dim3(64, 16, L_), 256, 0, stream>>>(W2, w2t,           2048, 512, (size_t)512 * 2048);
  embed_kernel<<<M_, 128, 0, stream>>>(x, emb, pe, xf, xb);

  for (int l = 0; l < L_; ++l) {
    gemm_kernel<<<dim3(12, 128), 256, 0, stream>>>(
        xb, wqkv + (size_t)l * 1536 * 512,
        bq + l * 512, bk + l * 512, bv + l * 512,
        qb, kb, vb, 512, 1536, 0, 1);
    attn_kernel<<<dim3(4, G_), 256, 0, stream>>>(qb, kb, vb, cxb);
    gemmln_kernel<<<512, 512, 0, stream>>>(
        cxb, wot + (size_t)l * 512 * 512, bo + l * 512, xf,
        g1 + l * 512, bn1 + l * 512, hf, hb, 512);
    gemm_kernel<<<dim3(16, 128), 256, 0, stream>>>(
        hb, w1t + (size_t)l * 2048 * 512,
        bf1 + l * 2048, nullptr, nullptr,
        f1b, nullptr, nullptr, 512, 2048, 1, 0);
    gemmln_kernel<<<512, 512, 0, stream>>>(
        f1b, w2t + (size_t)l * 512 * 2048, bf2 + l * 512, hf,
        g2 + l * 512, bn2 + l * 512, xf, xb, 2048);
  }

  fc_part_kernel<<<dim3(4, 256), 256, 0, stream>>>(xf, Wfc, part);
  fc_reduce_kernel<<<dim3(4, 32), 256, 0, stream>>>(part, bfc, out);
}

// Round 5
// 2189.234 us; speedup vs baseline: 1.3412x; 1.0609x over previous
//
#include <hip/hip_runtime.h>
#include <cstdint>
#include <cstddef>

#define S_  512
#define B_  32
#define D_  512
#define FF_ 2048
#define L_  6
#define O_  1000
#define M_  (B_*S_)     // 16384 rows of activations
#define G_  256         // attention groups (buggy reshape semantics)
#define DH_ 64

typedef __attribute__((ext_vector_type(8))) short bf16x8;
typedef __attribute__((ext_vector_type(4))) float f32x4;
typedef __attribute__((ext_vector_type(16))) float f32x16;

__device__ __forceinline__ unsigned short f2bf(float f) {
  unsigned int u = __builtin_bit_cast(unsigned int, f);
  u = (u + 0x7fffu + ((u >> 16) & 1u)) >> 16;
  return (unsigned short)u;
}
__device__ __forceinline__ float bf2f(unsigned short u) {
  return __builtin_bit_cast(float, (unsigned int)u << 16);
}
__device__ __forceinline__ unsigned int pkbf(float a, float b) {
  return (unsigned int)f2bf(a) | ((unsigned int)f2bf(b) << 16);
}
__device__ __forceinline__ void gload_lds16(const void* g, void* l) {
  __builtin_amdgcn_global_load_lds(
      (const __attribute__((address_space(1))) unsigned int*)g,
      (__attribute__((address_space(3))) unsigned int*)l, 16, 0, 0);
}

// ---------------- positional encoding table [512][512] f32 ----------------
__global__ void pe_kernel(float* __restrict__ pe) {
  int i = blockIdx.x * 256 + threadIdx.x;
  int s = i >> 9, d = i & 511;
  double de = (double)(d & ~1);
  double ang = (double)s * exp(de * (-9.210340371976184 / 512.0));
  pe[i] = (d & 1) ? (float)cos(ang) : (float)sin(ang);
}

// ------------- transpose-convert W [z][K][N] f32 -> Wt [z-stride ozs][N][K] bf16 -------------
__global__ void wconv_kernel(const float* __restrict__ W, unsigned short* __restrict__ Wt,
                             int K, int N, size_t ozs) {
  __shared__ float tile[32][33];
  const float* Wl = W + (size_t)blockIdx.z * K * N;
  unsigned short* Wtl = Wt + (size_t)blockIdx.z * ozs;
  int k0 = blockIdx.x * 32, n0 = blockIdx.y * 32;
  int c = threadIdx.x & 31, rb = threadIdx.x >> 5;
#pragma unroll
  for (int i = 0; i < 4; ++i) {
    int r = rb + i * 8;
    tile[r][c] = Wl[(size_t)(k0 + r) * N + n0 + c];
  }
  __syncthreads();
#pragma unroll
  for (int i = 0; i < 4; ++i) {
    int r = rb + i * 8;
    Wtl[(size_t)(n0 + r) * K + k0 + c] = f2bf(tile[c][r]);
  }
}

// ------------- embedding + PE (bf16 out only) -------------
__global__ void embed_kernel(const int* __restrict__ x, const float* __restrict__ emb,
                             const float* __restrict__ pe, unsigned short* __restrict__ xb) {
  int bi = blockIdx.x;            // s*B + b
  int s = bi / B_, b = bi % B_;
  int tok = x[s * B_ + b];
  int d = threadIdx.x * 4;
  float4 e = *(const float4*)(emb + (size_t)tok * D_ + d);
  float4 p = *(const float4*)(pe + (size_t)s * D_ + d);
  size_t o = ((size_t)b * S_ + s) * D_ + d;
  ushort4 u;
  u.x = f2bf(e.x + p.x); u.y = f2bf(e.y + p.y);
  u.z = f2bf(e.z + p.z); u.w = f2bf(e.w + p.w);
  *(ushort4*)(xb + o) = u;
}

// ------------- bf16 MFMA GEMM, 128x128 tile, BK=32, triple-buffered counted-vmcnt pipeline -------------
// grid: 1D, nbx = N/128, nby = M/128, XCD-swizzled. 256 threads.
__global__ __launch_bounds__(256) void gemm_kernel(
    const unsigned short* __restrict__ A, const unsigned short* __restrict__ Bt,
    const float* __restrict__ b0, const float* __restrict__ b1, const float* __restrict__ b2,
    unsigned short* __restrict__ o0, unsigned short* __restrict__ o1, unsigned short* __restrict__ o2,
    int K, int N, int relu, int split, int nbx) {
  __shared__ unsigned short As[3][128 * 32];
  __shared__ unsigned short Bs[3][128 * 32];
  // bijective XCD swizzle (nwg % 8 == 0 for all our launches)
  int nwg = nbx * (M_ / 128);
  int cpx = nwg >> 3;
  int id = blockIdx.x;
  int wg = (id % 8) * cpx + id / 8;
  int bx = wg % nbx, by = wg / nbx;
  int m0 = by * 128, n0 = bx * 128;

  int tid = threadIdx.x, lane = tid & 63, wid = tid >> 6;
  int wm = wid >> 1, wn = wid & 1;
  f32x4 acc[4][4];
#pragma unroll
  for (int mi = 0; mi < 4; ++mi)
#pragma unroll
    for (int ni = 0; ni < 4; ++ni) acc[mi][ni] = (f32x4)0.0f;

  int srow = lane >> 2, scol = (lane & 3) * 8;
  const unsigned short* Abase = A + (size_t)m0 * K;
  const unsigned short* Bbase = Bt + (size_t)n0 * K;
  int c16 = lane & 15, hi = lane >> 4;
  int koff = hi * 8;
  int arow = wm * 64 + c16, brow = wn * 64 + c16;
  int nk = K >> 5;   // requires nk >= 3 (true for K=512/2048)

  auto STAGE = [&](int kt, int bb) {
    int k0 = kt * 32;
#pragma unroll
    for (int i = 0; i < 2; ++i) {
      int c = wid * 2 + i;
      gload_lds16(Abase + (size_t)(c * 16 + srow) * K + k0 + scol, (char*)As[bb] + c * 1024);
      gload_lds16(Bbase + (size_t)(c * 16 + srow) * K + k0 + scol, (char*)Bs[bb] + c * 1024);
    }
  };

  STAGE(0, 0); STAGE(1, 1); STAGE(2, 2);
  int bb = 0;
  for (int kt = 0; kt < nk; ++kt) {
    int rem = nk - 1 - kt;
    if (rem >= 2)      asm volatile("s_waitcnt vmcnt(8)" ::: "memory");
    else if (rem == 1) asm volatile("s_waitcnt vmcnt(4)" ::: "memory");
    else               asm volatile("s_waitcnt vmcnt(0)" ::: "memory");
    __builtin_amdgcn_s_barrier();       // tile kt visible to all waves
    __builtin_amdgcn_sched_barrier(0);
    bf16x8 af[4], bfr[4];
#pragma unroll
    for (int mi = 0; mi < 4; ++mi) af[mi] = *(const bf16x8*)&As[bb][(arow + mi * 16) * 32 + koff];
#pragma unroll
    for (int ni = 0; ni < 4; ++ni) bfr[ni] = *(const bf16x8*)&Bs[bb][(brow + ni * 16) * 32 + koff];
    __builtin_amdgcn_s_setprio(1);
#pragma unroll
    for (int mi = 0; mi < 4; ++mi)
#pragma unroll
      for (int ni = 0; ni < 4; ++ni)
        acc[mi][ni] = __builtin_amdgcn_mfma_f32_16x16x32_bf16(bfr[ni], af[mi], acc[mi][ni], 0, 0, 0);
    __builtin_amdgcn_s_setprio(0);
    __builtin_amdgcn_sched_barrier(0);
    __builtin_amdgcn_s_barrier();       // all waves done reading buf bb
    if (kt + 3 < nk) STAGE(kt + 3, bb);
    bb = (bb == 2) ? 0 : bb + 1;
  }

  const float* bias = b0;
  unsigned short* outb = o0;
  int nbase = n0, ostride = N;
  if (split) {
    int seg = n0 >> 9;
    if (seg == 1) { bias = b1; outb = o1; }
    else if (seg == 2) { bias = b2; outb = o2; }
    nbase = n0 & 511; ostride = 512;
  }
  // swapped layout: lane holds row = ...+c16, cols = ...+hi*4+{0..3}
#pragma unroll
  for (int ni = 0; ni < 4; ++ni) {
    int colb = nbase + wn * 64 + ni * 16 + hi * 4;
    float4 bv = *(const float4*)(bias + colb);
#pragma unroll
    for (int mi = 0; mi < 4; ++mi) {
      int row = m0 + wm * 64 + mi * 16 + c16;
      float v0 = acc[mi][ni][0] + bv.x;
      float v1 = acc[mi][ni][1] + bv.y;
      float v2 = acc[mi][ni][2] + bv.z;
      float v3 = acc[mi][ni][3] + bv.w;
      if (relu) { v0 = fmaxf(v0, 0.f); v1 = fmaxf(v1, 0.f); v2 = fmaxf(v2, 0.f); v3 = fmaxf(v3, 0.f); }
      *(uint2*)(outb + (size_t)row * ostride + colb) = make_uint2(pkbf(v0, v1), pkbf(v2, v3));
    }
  }
}

// ------------- fused GEMM (BM=32 x BN=512) + bias + bf16-residual + LayerNorm -------------
// 512 threads = 8 waves, each wave owns 64 cols; grid = M/32 = 512 blocks
__global__ __launch_bounds__(512) void gemmln_kernel(
    const unsigned short* __restrict__ A, const unsigned short* __restrict__ Bt,
    const float* __restrict__ bias, const unsigned short* __restrict__ resid,
    const float* __restrict__ g, const float* __restrict__ bvec,
    unsigned short* __restrict__ Yb, int K) {
  __shared__ unsigned short As[32 * 32];
  __shared__ unsigned short Bs[512 * 32];
  __shared__ float redS[8][32];
  __shared__ float redQ[8][32];
  int tid = threadIdx.x, lane = tid & 63, wid = tid >> 6;
  int wn = wid;                       // 0..7, 64-col slice
  int m0 = blockIdx.x * 32;
  f32x4 acc[2][4];
#pragma unroll
  for (int mi = 0; mi < 2; ++mi)
#pragma unroll
    for (int ni = 0; ni < 4; ++ni) acc[mi][ni] = (f32x4)0.0f;

  int srow = lane >> 2, scol = (lane & 3) * 8;
  int c16 = lane & 15, hi = lane >> 4;
  int koff = hi * 8;
  int nk = K >> 5;
  for (int kt = 0; kt < nk; ++kt) {
    int k0 = kt * 32;
#pragma unroll
    for (int i = 0; i < 4; ++i) {
      int c = wid * 4 + i;   // 32 chunks of 1KB covering Bs[512][32]
      gload_lds16(Bt + (size_t)(c * 16 + srow) * K + k0 + scol, (char*)Bs + c * 1024);
    }
    if (wid < 2)
      gload_lds16(A + (size_t)(m0 + wid * 16 + srow) * K + k0 + scol, (char*)As + wid * 1024);
    __syncthreads();
    bf16x8 af[2], bfr[4];
#pragma unroll
    for (int mi = 0; mi < 2; ++mi) af[mi] = *(const bf16x8*)&As[(mi * 16 + c16) * 32 + koff];
#pragma unroll
    for (int ni = 0; ni < 4; ++ni) bfr[ni] = *(const bf16x8*)&Bs[(wn * 64 + ni * 16 + c16) * 32 + koff];
#pragma unroll
    for (int mi = 0; mi < 2; ++mi)
#pragma unroll
      for (int ni = 0; ni < 4; ++ni)
        acc[mi][ni] = __builtin_amdgcn_mfma_f32_16x16x32_bf16(bfr[ni], af[mi], acc[mi][ni], 0, 0, 0);
    __syncthreads();
  }

  // acc += bias + resid(bf16)
#pragma unroll
  for (int ni = 0; ni < 4; ++ni) {
    int colb = wn * 64 + ni * 16 + hi * 4;
    float4 bv = *(const float4*)(bias + colb);
#pragma unroll
    for (int mi = 0; mi < 2; ++mi) {
      int row = m0 + mi * 16 + c16;
      ushort4 rv = *(const ushort4*)(resid + (size_t)row * 512 + colb);
      acc[mi][ni][0] += bv.x + bf2f(rv.x);
      acc[mi][ni][1] += bv.y + bf2f(rv.y);
      acc[mi][ni][2] += bv.z + bf2f(rv.z);
      acc[mi][ni][3] += bv.w + bf2f(rv.w);
    }
  }
  // row sums
  float mean_[2], rstd_[2];
#pragma unroll
  for (int mi = 0; mi < 2; ++mi) {
    float s = 0.0f;
#pragma unroll
    for (int ni = 0; ni < 4; ++ni)
#pragma unroll
      for (int r = 0; r < 4; ++r) s += acc[mi][ni][r];
    s += __shfl_xor(s, 16);
    s += __shfl_xor(s, 32);
    if (lane < 16) redS[wn][mi * 16 + lane] = s;
  }
  __syncthreads();
#pragma unroll
  for (int mi = 0; mi < 2; ++mi) {
    int rl = mi * 16 + c16;
    float s = 0.0f;
#pragma unroll
    for (int w = 0; w < 8; ++w) s += redS[w][rl];
    mean_[mi] = s * (1.0f / 512.0f);
  }
  // centered square sums
#pragma unroll
  for (int mi = 0; mi < 2; ++mi) {
    float ss = 0.0f;
#pragma unroll
    for (int ni = 0; ni < 4; ++ni)
#pragma unroll
      for (int r = 0; r < 4; ++r) {
        float d = acc[mi][ni][r] - mean_[mi];
        ss += d * d;
      }
    ss += __shfl_xor(ss, 16);
    ss += __shfl_xor(ss, 32);
    if (lane < 16) redQ[wn][mi * 16 + lane] = ss;
  }
  __syncthreads();
#pragma unroll
  for (int mi = 0; mi < 2; ++mi) {
    int rl = mi * 16 + c16;
    float ss = 0.0f;
#pragma unroll
    for (int w = 0; w < 8; ++w) ss += redQ[w][rl];
    rstd_[mi] = rsqrtf(ss * (1.0f / 512.0f) + 1e-5f);
  }
  // normalize + write bf16
#pragma unroll
  for (int mi = 0; mi < 2; ++mi) {
    float mu = mean_[mi], rs = rstd_[mi];
    int row = m0 + mi * 16 + c16;
#pragma unroll
    for (int ni = 0; ni < 4; ++ni) {
      int colb = wn * 64 + ni * 16 + hi * 4;
      float4 gg = *(const float4*)(g + colb);
      float4 bb = *(const float4*)(bvec + colb);
      float y0 = (acc[mi][ni][0] - mu) * rs * gg.x + bb.x;
      float y1 = (acc[mi][ni][1] - mu) * rs * gg.y + bb.y;
      float y2 = (acc[mi][ni][2] - mu) * rs * gg.z + bb.z;
      float y3 = (acc[mi][ni][3] - mu) * rs * gg.w + bb.w;
      *(uint2*)(Yb + (size_t)row * 512 + colb) = make_uint2(pkbf(y0, y1), pkbf(y2, y3));
    }
  }
}

// ------------- flash attention, 32x32 swapped-QK^T, in-register softmax -------------
__global__ __launch_bounds__(256) void attn_kernel(
    const unsigned short* __restrict__ Q, const unsigned short* __restrict__ Kb,
    const unsigned short* __restrict__ Vb, unsigned short* __restrict__ Ctx) {
  __shared__ char KlB[8192];   // K tile [64 k][64 d] bf16, XOR-swizzled rows
  __shared__ char VtB[8192];   // V^T tile [64 d][64 k] bf16, XOR-swizzled rows
  int g = blockIdx.y;
  int q0 = blockIdx.x * 128;
  const unsigned short* Kg = Kb + (size_t)g * 512 * 64;
  const unsigned short* Vg = Vb + (size_t)g * 512 * 64;
  int tid = threadIdx.x, lane = tid & 63, wid = tid >> 6;
  int l31 = lane & 31, h = lane >> 5;
  bool lo = (lane < 32);
  int qrow = q0 + wid * 32 + l31;
  const float sc2 = 0.125f * 1.44269504f;

  bf16x8 qf[4];
  {
    const unsigned short* qp = Q + ((size_t)g * 512 + qrow) * 64;
#pragma unroll
    for (int c = 0; c < 4; ++c) {
      bf16x8 raw = *(const bf16x8*)(qp + c * 16 + h * 8);
      union { unsigned int u[4]; bf16x8 v; } uu;
#pragma unroll
      for (int j = 0; j < 4; ++j)
        uu.u[j] = pkbf(bf2f((unsigned short)raw[2 * j]) * sc2,
                       bf2f((unsigned short)raw[2 * j + 1]) * sc2);
      qf[c] = uu.v;
    }
  }

  f32x16 c0 = (f32x16)0.0f, c1 = (f32x16)0.0f;   // O^T[d][q], d-halves
  float mr = -3.0e38f, ls = 0.0f;

  for (int kt = 0; kt < 8; ++kt) {
    __syncthreads();
    {
      int row = tid >> 2;
      size_t base = (size_t)(kt * 64 + row) * 64;
#pragma unroll
      for (int i = 0; i < 2; ++i) {
        int cb = ((tid & 3) + 4 * i) * 16;       // byte col within 128B row
        bf16x8 kv = *(const bf16x8*)(Kg + base + cb / 2);
        *(bf16x8*)(KlB + row * 128 + (cb ^ ((row & 7) << 4))) = kv;
        bf16x8 vv = *(const bf16x8*)(Vg + base + cb / 2);
#pragma unroll
        for (int j = 0; j < 8; ++j) {
          int d = cb / 2 + j;
          *(unsigned short*)(VtB + d * 128 + ((2 * row) ^ ((d & 7) << 4))) =
              (unsigned short)vv[j];
        }
      }
    }
    __syncthreads();

    f32x16 s0 = (f32x16)0.0f, s1 = (f32x16)0.0f;
#pragma unroll
    for (int c = 0; c < 4; ++c) {
      int cb = 32 * c + 16 * h;
      int sw = cb ^ ((l31 & 7) << 4);
      bf16x8 k0 = *(const bf16x8*)(KlB + l31 * 128 + sw);
      bf16x8 k1 = *(const bf16x8*)(KlB + (32 + l31) * 128 + sw);
      s0 = __builtin_amdgcn_mfma_f32_32x32x16_bf16(k0, qf[c], s0, 0, 0, 0);
      s1 = __builtin_amdgcn_mfma_f32_32x32x16_bf16(k1, qf[c], s1, 0, 0, 0);
    }

    float pm = s0[0];
#pragma unroll
    for (int i = 1; i < 16; ++i) pm = fmaxf(pm, s0[i]);
#pragma unroll
    for (int i = 0; i < 16; ++i) pm = fmaxf(pm, s1[i]);
    pm = fmaxf(pm, __shfl_xor(pm, 32));
    float mnew = fmaxf(mr, pm);
    float alpha = exp2f(mr - mnew);
    mr = mnew;
    float p[32];
    float rs = 0.0f;
#pragma unroll
    for (int i = 0; i < 16; ++i) { p[i] = exp2f(s0[i] - mnew); rs += p[i]; }
#pragma unroll
    for (int i = 0; i < 16; ++i) { p[16 + i] = exp2f(s1[i] - mnew); rs += p[16 + i]; }
    float rso = __shfl_xor(rs, 32);
    ls = ls * alpha + rs + rso;
#pragma unroll
    for (int i = 0; i < 16; ++i) { c0[i] *= alpha; c1[i] *= alpha; }

    union { unsigned int u[4]; bf16x8 v; } pa[4];
#pragma unroll
    for (int t = 0; t < 2; ++t) {
#pragma unroll
      for (int u = 0; u < 2; ++u) {
#pragma unroll
        for (int pr = 0; pr < 2; ++pr) {
          const int b0i = t * 16 + 8 * u;
          unsigned int a  = pkbf(p[b0i + 2 * pr],     p[b0i + 2 * pr + 1]);
          unsigned int b  = pkbf(p[b0i + 4 + 2 * pr], p[b0i + 4 + 2 * pr + 1]);
          unsigned int sa = __shfl_xor(a, 32);
          unsigned int sb = __shfl_xor(b, 32);
          pa[t * 2 + u].u[pr]     = lo ? a  : sb;
          pa[t * 2 + u].u[2 + pr] = lo ? sa : b;
        }
      }
    }

#pragma unroll
    for (int kc = 0; kc < 4; ++kc) {
      int cb = 32 * kc + 16 * h;
      int sw = cb ^ ((l31 & 7) << 4);
      bf16x8 v0 = *(const bf16x8*)(VtB + l31 * 128 + sw);
      bf16x8 v1 = *(const bf16x8*)(VtB + (32 + l31) * 128 + sw);
      c0 = __builtin_amdgcn_mfma_f32_32x32x16_bf16(v0, pa[kc].v, c0, 0, 0, 0);
      c1 = __builtin_amdgcn_mfma_f32_32x32x16_bf16(v1, pa[kc].v, c1, 0, 0, 0);
    }
  }

  float inv = 1.0f / ls;
  unsigned short* cp = Ctx + ((size_t)g * 512 + qrow) * 64;
#pragma unroll
  for (int dh = 0; dh < 2; ++dh) {
#pragma unroll
    for (int rq = 0; rq < 4; ++rq) {
      float e0 = (dh ? c1[rq * 4 + 0] : c0[rq * 4 + 0]) * inv;
      float e1 = (dh ? c1[rq * 4 + 1] : c0[rq * 4 + 1]) * inv;
      float e2 = (dh ? c1[rq * 4 + 2] : c0[rq * 4 + 2]) * inv;
      float e3 = (dh ? c1[rq * 4 + 3] : c0[rq * 4 + 3]) * inv;
      int d0 = dh * 32 + rq * 8 + h * 4;
      *(uint2*)(cp + d0) = make_uint2(pkbf(e0, e1), pkbf(e2, e3));
    }
  }
}

// ------------- final FC: out[32][1000] = act[32][262144](bf16) @ Wfc + bfc (split-K) -------------
#define KCH 1024
__global__ __launch_bounds__(256) void fc_part_kernel(const unsigned short* __restrict__ act,
                                                      const float* __restrict__ Wfc,
                                                      float* __restrict__ part) {
  __shared__ float al[32][256];
  int o = blockIdx.x * 256 + threadIdx.x;
  int kc = blockIdx.y;
  size_t k0 = (size_t)kc * KCH;
  float acc[32];
#pragma unroll
  for (int bb = 0; bb < 32; ++bb) acc[bb] = 0.0f;
  for (int sub = 0; sub < KCH / 256; ++sub) {
    __syncthreads();
    for (int i = threadIdx.x; i < 32 * 128; i += 256) {
      int bb = i >> 7, kk = (i & 127) * 2;
      ushort2 u = *(const ushort2*)(act + (size_t)bb * 262144 + k0 + sub * 256 + kk);
      al[bb][kk] = bf2f(u.x);
      al[bb][kk + 1] = bf2f(u.y);
    }
    __syncthreads();
    if (o < O_) {
      const float* wp = Wfc + (k0 + sub * 256) * O_ + o;
      for (int kk = 0; kk < 256; ++kk) {
        float w = wp[(size_t)kk * O_];
#pragma unroll
        for (int bb = 0; bb < 32; ++bb) acc[bb] = fmaf(al[bb][kk], w, acc[bb]);
      }
    }
  }
  if (o < O_) {
#pragma unroll
    for (int bb = 0; bb < 32; ++bb) part[((size_t)kc * 32 + bb) * O_ + o] = acc[bb];
  }
}

__global__ void fc_reduce_kernel(const float* __restrict__ part, const float* __restrict__ bfc,
                                 float* __restrict__ out) {
  int o = blockIdx.x * 256 + threadIdx.x;
  int b = blockIdx.y;
  if (o >= O_) return;
  float s = bfc[o];
  for (int c = 0; c < 256; ++c) s += part[((size_t)c * 32 + b) * O_ + o];
  out[(size_t)b * O_ + o] = s;
}

extern "C" void kernel_launch(void* const* d_in, const int* in_sizes, int n_in,
                              void* d_out, int out_size, void* d_ws, size_t ws_size,
                              hipStream_t stream) {
  const int*   x   = (const int*)d_in[0];
  const float* emb = (const float*)d_in[2];
  const float* Wq  = (const float*)d_in[3];
  const float* bq  = (const float*)d_in[4];
  const float* Wk  = (const float*)d_in[5];
  const float* bk  = (const float*)d_in[6];
  const float* Wv  = (const float*)d_in[7];
  const float* bv  = (const float*)d_in[8];
  const float* Wo  = (const float*)d_in[9];
  const float* bo  = (const float*)d_in[10];
  const float* g1  = (const float*)d_in[11];
  const float* bn1 = (const float*)d_in[12];
  const float* W1  = (const float*)d_in[13];
  const float* bf1 = (const float*)d_in[14];
  const float* W2  = (const float*)d_in[15];
  const float* bf2 = (const float*)d_in[16];
  const float* g2  = (const float*)d_in[17];
  const float* bn2 = (const float*)d_in[18];
  const float* Wfc = (const float*)d_in[19];
  const float* bfc = (const float*)d_in[20];
  float* out = (float*)d_out;

  char* ws = (char*)d_ws;
  size_t off = 0;
  auto take = [&](size_t bytes) { char* p = ws + off; off += (bytes + 255) & ~(size_t)255; return p; };
  float*          pe   = (float*)take((size_t)512 * 512 * 4);
  unsigned short* wqkv = (unsigned short*)take((size_t)L_ * 1536 * 512 * 2);
  unsigned short* wot  = (unsigned short*)take((size_t)L_ * 512 * 512 * 2);
  unsigned short* w1t  = (unsigned short*)take((size_t)L_ * 2048 * 512 * 2);
  unsigned short* w2t  = (unsigned short*)take((size_t)L_ * 512 * 2048 * 2);
  unsigned short* xb   = (unsigned short*)take((size_t)M_ * 512 * 2);
  unsigned short* qb   = (unsigned short*)take((size_t)M_ * 512 * 2);
  unsigned short* kb   = (unsigned short*)take((size_t)M_ * 512 * 2);
  unsigned short* vb   = (unsigned short*)take((size_t)M_ * 512 * 2);
  unsigned short* cxb  = (unsigned short*)take((size_t)M_ * 512 * 2);
  unsigned short* hb   = (unsigned short*)take((size_t)M_ * 512 * 2);
  unsigned short* f1b  = qb;          // alias: q/k/v region (3x16.8MB >= 67MB? q+k+v+cxb = 67MB) free during FFN
  float*          part = (float*)qb;  // alias: free after last layer

  pe_kernel<<<1024, 256, 0, stream>>>(pe);
  wconv_kernel<<<dim3(16, 16, L_), 256, 0, stream>>>(Wq, wqkv,          512, 512,  (size_t)1536 * 512);
  wconv_kernel<<<dim3(16, 16, L_), 256, 0, stream>>>(Wk, wqkv + 262144, 512, 512,  (size_t)1536 * 512);
  wconv_kernel<<<dim3(16, 16, L_), 256, 0, stream>>>(Wv, wqkv + 524288, 512, 512,  (size_t)1536 * 512);
  wconv_kernel<<<dim3(16, 16, L_), 256, 0, stream>>>(Wo, wot,           512, 512,  (size_t)512 * 512);
  wconv_kernel<<<dim3(16, 64, L_), 256, 0, stream>>>(W1, w1t,           512, 2048, (size_t)2048 * 512);
  wconv_kernel<<<dim3(64, 16, L_), 256, 0, stream>>>(W2, w2t,           2048, 512, (size_t)512 * 2048);
  embed_kernel<<<M_, 128, 0, stream>>>(x, emb, pe, xb);

  for (int l = 0; l < L_; ++l) {
    gemm_kernel<<<12 * 128, 256, 0, stream>>>(
        xb, wqkv + (size_t)l * 1536 * 512,
        bq + l * 512, bk + l * 512, bv + l * 512,
        qb, kb, vb, 512, 1536, 0, 1, 12);
    attn_kernel<<<dim3(4, G_), 256, 0, stream>>>(qb, kb, vb, cxb);
    gemmln_kernel<<<512, 512, 0, stream>>>(
        cxb, wot + (size_t)l * 512 * 512, bo + l * 512, xb,
        g1 + l * 512, bn1 + l * 512, hb, 512);
    gemm_kernel<<<16 * 128, 256, 0, stream>>>(
        hb, w1t + (size_t)l * 2048 * 512,
        bf1 + l * 2048, nullptr, nullptr,
        f1b, nullptr, nullptr, 512, 2048, 1, 0, 16);
    gemmln_kernel<<<512, 512, 0, stream>>>(
        f1b, w2t + (size_t)l * 512 * 2048, bf2 + l * 512, hb,
        g2 + l * 512, bn2 + l * 512, xb, 2048);
  }

  fc_part_kernel<<<dim3(4, 256), 256, 0, stream>>>(xb, Wfc, part);
  fc_reduce_kernel<<<dim3(4, 32), 256, 0, stream>>>(part, bfc, out);
}

// Round 6
// 2120.592 us; speedup vs baseline: 1.3846x; 1.0324x over previous
//
#include <hip/hip_runtime.h>
#include <cstdint>
#include <cstddef>

#define S_  512
#define B_  32
#define D_  512
#define FF_ 2048
#define L_  6
#define O_  1000
#define M_  (B_*S_)     // 16384 rows of activations
#define G_  256         // attention groups (buggy reshape semantics)
#define DH_ 64

typedef __attribute__((ext_vector_type(8))) short bf16x8;
typedef __attribute__((ext_vector_type(4))) float f32x4;
typedef __attribute__((ext_vector_type(16))) float f32x16;

__device__ __forceinline__ unsigned short f2bf(float f) {
  unsigned int u = __builtin_bit_cast(unsigned int, f);
  u = (u + 0x7fffu + ((u >> 16) & 1u)) >> 16;
  return (unsigned short)u;
}
__device__ __forceinline__ float bf2f(unsigned short u) {
  return __builtin_bit_cast(float, (unsigned int)u << 16);
}
__device__ __forceinline__ unsigned int pkbf(float a, float b) {
  return (unsigned int)f2bf(a) | ((unsigned int)f2bf(b) << 16);
}
__device__ __forceinline__ void gload_lds16(const void* g, void* l) {
  __builtin_amdgcn_global_load_lds(
      (const __attribute__((address_space(1))) unsigned int*)g,
      (__attribute__((address_space(3))) unsigned int*)l, 16, 0, 0);
}

// ---------------- positional encoding table [512][512] f32 ----------------
__global__ void pe_kernel(float* __restrict__ pe) {
  int i = blockIdx.x * 256 + threadIdx.x;
  int s = i >> 9, d = i & 511;
  double de = (double)(d & ~1);
  double ang = (double)s * exp(de * (-9.210340371976184 / 512.0));
  pe[i] = (d & 1) ? (float)cos(ang) : (float)sin(ang);
}

// ------------- transpose-convert W [z][K][N] f32 -> Wt [z-stride ozs][N][K] bf16 -------------
__global__ void wconv_kernel(const float* __restrict__ W, unsigned short* __restrict__ Wt,
                             int K, int N, size_t ozs) {
  __shared__ float tile[32][33];
  const float* Wl = W + (size_t)blockIdx.z * K * N;
  unsigned short* Wtl = Wt + (size_t)blockIdx.z * ozs;
  int k0 = blockIdx.x * 32, n0 = blockIdx.y * 32;
  int c = threadIdx.x & 31, rb = threadIdx.x >> 5;
#pragma unroll
  for (int i = 0; i < 4; ++i) {
    int r = rb + i * 8;
    tile[r][c] = Wl[(size_t)(k0 + r) * N + n0 + c];
  }
  __syncthreads();
#pragma unroll
  for (int i = 0; i < 4; ++i) {
    int r = rb + i * 8;
    Wtl[(size_t)(n0 + r) * K + k0 + c] = f2bf(tile[c][r]);
  }
}

// ------------- embedding + PE (bf16 out only) -------------
__global__ void embed_kernel(const int* __restrict__ x, const float* __restrict__ emb,
                             const float* __restrict__ pe, unsigned short* __restrict__ xb) {
  int bi = blockIdx.x;            // s*B + b
  int s = bi / B_, b = bi % B_;
  int tok = x[s * B_ + b];
  int d = threadIdx.x * 4;
  float4 e = *(const float4*)(emb + (size_t)tok * D_ + d);
  float4 p = *(const float4*)(pe + (size_t)s * D_ + d);
  size_t o = ((size_t)b * S_ + s) * D_ + d;
  ushort4 u;
  u.x = f2bf(e.x + p.x); u.y = f2bf(e.y + p.y);
  u.z = f2bf(e.z + p.z); u.w = f2bf(e.w + p.w);
  *(ushort4*)(xb + o) = u;
}

// ------------- bf16 MFMA GEMM, 128(M)x256(N) tile, BK=32, triple-buffered counted-vmcnt -------------
// 512 threads = 8 waves (2M x 4N), per-wave 64x64 out. grid 1D XCD-swizzled.
__global__ __launch_bounds__(512) void gemm_kernel(
    const unsigned short* __restrict__ A, const unsigned short* __restrict__ Bt,
    const float* __restrict__ b0, const float* __restrict__ b1, const float* __restrict__ b2,
    unsigned short* __restrict__ o0, unsigned short* __restrict__ o1, unsigned short* __restrict__ o2,
    int K, int N, int relu, int split, int nbx) {
  __shared__ unsigned short As[3][128 * 32];   // 8 KB each
  __shared__ unsigned short Bs[3][256 * 32];   // 16 KB each
  int nwg = nbx * (M_ / 128);
  int cpx = nwg >> 3;
  int id = blockIdx.x;
  int wg = (id % 8) * cpx + id / 8;            // bijective: nwg % 8 == 0 for all launches
  int bx = wg % nbx, by = wg / nbx;
  int m0 = by * 128, n0 = bx * 256;

  int tid = threadIdx.x, lane = tid & 63, wid = tid >> 6;
  int wm = wid >> 2, wn = wid & 3;
  f32x4 acc[4][4];
#pragma unroll
  for (int mi = 0; mi < 4; ++mi)
#pragma unroll
    for (int ni = 0; ni < 4; ++ni) acc[mi][ni] = (f32x4)0.0f;

  int srow = lane >> 2, scol = (lane & 3) * 8;
  const unsigned short* Abase = A + (size_t)m0 * K;
  const unsigned short* Bbase = Bt + (size_t)n0 * K;
  int c16 = lane & 15, hi = lane >> 4;
  int koff = hi * 8;
  int arow = wm * 64 + c16, brow = wn * 64 + c16;
  int nk = K >> 5;   // >= 3 for all our K

  auto STAGE = [&](int kt, int bb) {
    int k0 = kt * 32;
    // A: 8 chunks of 1KB, one per wave
    gload_lds16(Abase + (size_t)(wid * 16 + srow) * K + k0 + scol, (char*)As[bb] + wid * 1024);
    // B: 16 chunks, two per wave
#pragma unroll
    for (int i = 0; i < 2; ++i) {
      int c = wid * 2 + i;
      gload_lds16(Bbase + (size_t)(c * 16 + srow) * K + k0 + scol, (char*)Bs[bb] + c * 1024);
    }
  };

  STAGE(0, 0); STAGE(1, 1); STAGE(2, 2);
  int bb = 0;
  for (int kt = 0; kt < nk; ++kt) {
    int rem = nk - 1 - kt;
    if (rem >= 2)      asm volatile("s_waitcnt vmcnt(6)" ::: "memory");
    else if (rem == 1) asm volatile("s_waitcnt vmcnt(3)" ::: "memory");
    else               asm volatile("s_waitcnt vmcnt(0)" ::: "memory");
    __builtin_amdgcn_s_barrier();       // tile kt visible to all waves
    __builtin_amdgcn_sched_barrier(0);
    bf16x8 af[4], bfr[4];
#pragma unroll
    for (int mi = 0; mi < 4; ++mi) af[mi] = *(const bf16x8*)&As[bb][(arow + mi * 16) * 32 + koff];
#pragma unroll
    for (int ni = 0; ni < 4; ++ni) bfr[ni] = *(const bf16x8*)&Bs[bb][(brow + ni * 16) * 32 + koff];
    __builtin_amdgcn_s_setprio(1);
#pragma unroll
    for (int mi = 0; mi < 4; ++mi)
#pragma unroll
      for (int ni = 0; ni < 4; ++ni)
        acc[mi][ni] = __builtin_amdgcn_mfma_f32_16x16x32_bf16(bfr[ni], af[mi], acc[mi][ni], 0, 0, 0);
    __builtin_amdgcn_s_setprio(0);
    __builtin_amdgcn_sched_barrier(0);
    __builtin_amdgcn_s_barrier();       // all waves done reading buf bb
    if (kt + 3 < nk) STAGE(kt + 3, bb);
    bb = (bb == 2) ? 0 : bb + 1;
  }

  const float* bias = b0;
  unsigned short* outb = o0;
  int nbase = n0, ostride = N;
  if (split) {                          // 256-tile lies in exactly one 512-col segment
    int seg = n0 >> 9;
    if (seg == 1) { bias = b1; outb = o1; }
    else if (seg == 2) { bias = b2; outb = o2; }
    nbase = n0 & 511; ostride = 512;
  }
  // swapped layout: lane holds row = ...+c16, cols = ...+hi*4+{0..3}
#pragma unroll
  for (int ni = 0; ni < 4; ++ni) {
    int colb = nbase + wn * 64 + ni * 16 + hi * 4;
    float4 bv = *(const float4*)(bias + colb);
#pragma unroll
    for (int mi = 0; mi < 4; ++mi) {
      int row = m0 + wm * 64 + mi * 16 + c16;
      float v0 = acc[mi][ni][0] + bv.x;
      float v1 = acc[mi][ni][1] + bv.y;
      float v2 = acc[mi][ni][2] + bv.z;
      float v3 = acc[mi][ni][3] + bv.w;
      if (relu) { v0 = fmaxf(v0, 0.f); v1 = fmaxf(v1, 0.f); v2 = fmaxf(v2, 0.f); v3 = fmaxf(v3, 0.f); }
      *(uint2*)(outb + (size_t)row * ostride + colb) = make_uint2(pkbf(v0, v1), pkbf(v2, v3));
    }
  }
}

// ------------- fused add-residual + LayerNorm (bf16 in, bf16 out), one row per block -------------
__global__ __launch_bounds__(128) void addln_kernel(
    const unsigned short* __restrict__ Y, const unsigned short* __restrict__ R,
    const float* __restrict__ g, const float* __restrict__ b,
    unsigned short* __restrict__ Out) {
  __shared__ float red[2], red2[2];
  int row = blockIdx.x, t = threadIdx.x;
  size_t o = (size_t)row * 512 + t * 4;
  ushort4 yv = *(const ushort4*)(Y + o);
  ushort4 rv = *(const ushort4*)(R + o);
  float v0 = bf2f(yv.x) + bf2f(rv.x);
  float v1 = bf2f(yv.y) + bf2f(rv.y);
  float v2 = bf2f(yv.z) + bf2f(rv.z);
  float v3 = bf2f(yv.w) + bf2f(rv.w);
  float s = v0 + v1 + v2 + v3;
#pragma unroll
  for (int m = 1; m < 64; m <<= 1) s += __shfl_xor(s, m);
  if ((t & 63) == 0) red[t >> 6] = s;
  __syncthreads();
  float mean = (red[0] + red[1]) * (1.0f / 512.0f);
  float d0 = v0 - mean, d1 = v1 - mean, d2 = v2 - mean, d3 = v3 - mean;
  float sq = d0 * d0 + d1 * d1 + d2 * d2 + d3 * d3;
#pragma unroll
  for (int m = 1; m < 64; m <<= 1) sq += __shfl_xor(sq, m);
  if ((t & 63) == 0) red2[t >> 6] = sq;
  __syncthreads();
  float var = (red2[0] + red2[1]) * (1.0f / 512.0f);
  float rstd = rsqrtf(var + 1e-5f);
  float4 gg = *(const float4*)(g + t * 4);
  float4 bb = *(const float4*)(b + t * 4);
  float y0 = d0 * rstd * gg.x + bb.x;
  float y1 = d1 * rstd * gg.y + bb.y;
  float y2 = d2 * rstd * gg.z + bb.z;
  float y3 = d3 * rstd * gg.w + bb.w;
  *(uint2*)(Out + o) = make_uint2(pkbf(y0, y1), pkbf(y2, y3));
}

// ------------- flash attention, 32x32 swapped-QK^T, in-register softmax -------------
__global__ __launch_bounds__(256) void attn_kernel(
    const unsigned short* __restrict__ Q, const unsigned short* __restrict__ Kb,
    const unsigned short* __restrict__ Vb, unsigned short* __restrict__ Ctx) {
  __shared__ char KlB[8192];   // K tile [64 k][64 d] bf16, XOR-swizzled rows
  __shared__ char VtB[8192];   // V^T tile [64 d][64 k] bf16, XOR-swizzled rows
  int g = blockIdx.y;
  int q0 = blockIdx.x * 128;
  const unsigned short* Kg = Kb + (size_t)g * 512 * 64;
  const unsigned short* Vg = Vb + (size_t)g * 512 * 64;
  int tid = threadIdx.x, lane = tid & 63, wid = tid >> 6;
  int l31 = lane & 31, h = lane >> 5;
  bool lo = (lane < 32);
  int qrow = q0 + wid * 32 + l31;
  const float sc2 = 0.125f * 1.44269504f;

  bf16x8 qf[4];
  {
    const unsigned short* qp = Q + ((size_t)g * 512 + qrow) * 64;
#pragma unroll
    for (int c = 0; c < 4; ++c) {
      bf16x8 raw = *(const bf16x8*)(qp + c * 16 + h * 8);
      union { unsigned int u[4]; bf16x8 v; } uu;
#pragma unroll
      for (int j = 0; j < 4; ++j)
        uu.u[j] = pkbf(bf2f((unsigned short)raw[2 * j]) * sc2,
                       bf2f((unsigned short)raw[2 * j + 1]) * sc2);
      qf[c] = uu.v;
    }
  }

  f32x16 c0 = (f32x16)0.0f, c1 = (f32x16)0.0f;   // O^T[d][q], d-halves
  float mr = -3.0e38f, ls = 0.0f;

  for (int kt = 0; kt < 8; ++kt) {
    __syncthreads();
    {
      int row = tid >> 2;
      size_t base = (size_t)(kt * 64 + row) * 64;
#pragma unroll
      for (int i = 0; i < 2; ++i) {
        int cb = ((tid & 3) + 4 * i) * 16;       // byte col within 128B row
        bf16x8 kv = *(const bf16x8*)(Kg + base + cb / 2);
        *(bf16x8*)(KlB + row * 128 + (cb ^ ((row & 7) << 4))) = kv;
        bf16x8 vv = *(const bf16x8*)(Vg + base + cb / 2);
#pragma unroll
        for (int j = 0; j < 8; ++j) {
          int d = cb / 2 + j;
          *(unsigned short*)(VtB + d * 128 + ((2 * row) ^ ((d & 7) << 4))) =
              (unsigned short)vv[j];
        }
      }
    }
    __syncthreads();

    f32x16 s0 = (f32x16)0.0f, s1 = (f32x16)0.0f;
#pragma unroll
    for (int c = 0; c < 4; ++c) {
      int cb = 32 * c + 16 * h;
      int sw = cb ^ ((l31 & 7) << 4);
      bf16x8 k0 = *(const bf16x8*)(KlB + l31 * 128 + sw);
      bf16x8 k1 = *(const bf16x8*)(KlB + (32 + l31) * 128 + sw);
      s0 = __builtin_amdgcn_mfma_f32_32x32x16_bf16(k0, qf[c], s0, 0, 0, 0);
      s1 = __builtin_amdgcn_mfma_f32_32x32x16_bf16(k1, qf[c], s1, 0, 0, 0);
    }

    float pm = s0[0];
#pragma unroll
    for (int i = 1; i < 16; ++i) pm = fmaxf(pm, s0[i]);
#pragma unroll
    for (int i = 0; i < 16; ++i) pm = fmaxf(pm, s1[i]);
    pm = fmaxf(pm, __shfl_xor(pm, 32));
    float mnew = fmaxf(mr, pm);
    float alpha = exp2f(mr - mnew);
    mr = mnew;
    float p[32];
    float rs = 0.0f;
#pragma unroll
    for (int i = 0; i < 16; ++i) { p[i] = exp2f(s0[i] - mnew); rs += p[i]; }
#pragma unroll
    for (int i = 0; i < 16; ++i) { p[16 + i] = exp2f(s1[i] - mnew); rs += p[16 + i]; }
    float rso = __shfl_xor(rs, 32);
    ls = ls * alpha + rs + rso;
#pragma unroll
    for (int i = 0; i < 16; ++i) { c0[i] *= alpha; c1[i] *= alpha; }

    union { unsigned int u[4]; bf16x8 v; } pa[4];
#pragma unroll
    for (int t = 0; t < 2; ++t) {
#pragma unroll
      for (int u = 0; u < 2; ++u) {
#pragma unroll
        for (int pr = 0; pr < 2; ++pr) {
          const int b0i = t * 16 + 8 * u;
          unsigned int a  = pkbf(p[b0i + 2 * pr],     p[b0i + 2 * pr + 1]);
          unsigned int b  = pkbf(p[b0i + 4 + 2 * pr], p[b0i + 4 + 2 * pr + 1]);
          unsigned int sa = __shfl_xor(a, 32);
          unsigned int sb = __shfl_xor(b, 32);
          pa[t * 2 + u].u[pr]     = lo ? a  : sb;
          pa[t * 2 + u].u[2 + pr] = lo ? sa : b;
        }
      }
    }

#pragma unroll
    for (int kc = 0; kc < 4; ++kc) {
      int cb = 32 * kc + 16 * h;
      int sw = cb ^ ((l31 & 7) << 4);
      bf16x8 v0 = *(const bf16x8*)(VtB + l31 * 128 + sw);
      bf16x8 v1 = *(const bf16x8*)(VtB + (32 + l31) * 128 + sw);
      c0 = __builtin_amdgcn_mfma_f32_32x32x16_bf16(v0, pa[kc].v, c0, 0, 0, 0);
      c1 = __builtin_amdgcn_mfma_f32_32x32x16_bf16(v1, pa[kc].v, c1, 0, 0, 0);
    }
  }

  float inv = 1.0f / ls;
  unsigned short* cp = Ctx + ((size_t)g * 512 + qrow) * 64;
#pragma unroll
  for (int dh = 0; dh < 2; ++dh) {
#pragma unroll
    for (int rq = 0; rq < 4; ++rq) {
      float e0 = (dh ? c1[rq * 4 + 0] : c0[rq * 4 + 0]) * inv;
      float e1 = (dh ? c1[rq * 4 + 1] : c0[rq * 4 + 1]) * inv;
      float e2 = (dh ? c1[rq * 4 + 2] : c0[rq * 4 + 2]) * inv;
      float e3 = (dh ? c1[rq * 4 + 3] : c0[rq * 4 + 3]) * inv;
      int d0 = dh * 32 + rq * 8 + h * 4;
      *(uint2*)(cp + d0) = make_uint2(pkbf(e0, e1), pkbf(e2, e3));
    }
  }
}

// ------------- final FC: out[32][1000] = act[32][262144](bf16) @ Wfc + bfc (split-K) -------------
#define KCH 1024
__global__ __launch_bounds__(256) void fc_part_kernel(const unsigned short* __restrict__ act,
                                                      const float* __restrict__ Wfc,
                                                      float* __restrict__ part) {
  __shared__ float al[32][256];
  int o = blockIdx.x * 256 + threadIdx.x;
  int kc = blockIdx.y;
  size_t k0 = (size_t)kc * KCH;
  float acc[32];
#pragma unroll
  for (int bb = 0; bb < 32; ++bb) acc[bb] = 0.0f;
  for (int sub = 0; sub < KCH / 256; ++sub) {
    __syncthreads();
    for (int i = threadIdx.x; i < 32 * 128; i += 256) {
      int bb = i >> 7, kk = (i & 127) * 2;
      ushort2 u = *(const ushort2*)(act + (size_t)bb * 262144 + k0 + sub * 256 + kk);
      al[bb][kk] = bf2f(u.x);
      al[bb][kk + 1] = bf2f(u.y);
    }
    __syncthreads();
    if (o < O_) {
      const float* wp = Wfc + (k0 + sub * 256) * O_ + o;
      for (int kk = 0; kk < 256; ++kk) {
        float w = wp[(size_t)kk * O_];
#pragma unroll
        for (int bb = 0; bb < 32; ++bb) acc[bb] = fmaf(al[bb][kk], w, acc[bb]);
      }
    }
  }
  if (o < O_) {
#pragma unroll
    for (int bb = 0; bb < 32; ++bb) part[((size_t)kc * 32 + bb) * O_ + o] = acc[bb];
  }
}

__global__ void fc_reduce_kernel(const float* __restrict__ part, const float* __restrict__ bfc,
                                 float* __restrict__ out) {
  int o = blockIdx.x * 256 + threadIdx.x;
  int b = blockIdx.y;
  if (o >= O_) return;
  float s = bfc[o];
  for (int c = 0; c < 256; ++c) s += part[((size_t)c * 32 + b) * O_ + o];
  out[(size_t)b * O_ + o] = s;
}

extern "C" void kernel_launch(void* const* d_in, const int* in_sizes, int n_in,
                              void* d_out, int out_size, void* d_ws, size_t ws_size,
                              hipStream_t stream) {
  const int*   x   = (const int*)d_in[0];
  const float* emb = (const float*)d_in[2];
  const float* Wq  = (const float*)d_in[3];
  const float* bq  = (const float*)d_in[4];
  const float* Wk  = (const float*)d_in[5];
  const float* bk  = (const float*)d_in[6];
  const float* Wv  = (const float*)d_in[7];
  const float* bv  = (const float*)d_in[8];
  const float* Wo  = (const float*)d_in[9];
  const float* bo  = (const float*)d_in[10];
  const float* g1  = (const float*)d_in[11];
  const float* bn1 = (const float*)d_in[12];
  const float* W1  = (const float*)d_in[13];
  const float* bf1 = (const float*)d_in[14];
  const float* W2  = (const float*)d_in[15];
  const float* bf2 = (const float*)d_in[16];
  const float* g2  = (const float*)d_in[17];
  const float* bn2 = (const float*)d_in[18];
  const float* Wfc = (const float*)d_in[19];
  const float* bfc = (const float*)d_in[20];
  float* out = (float*)d_out;

  char* ws = (char*)d_ws;
  size_t off = 0;
  auto take = [&](size_t bytes) { char* p = ws + off; off += (bytes + 255) & ~(size_t)255; return p; };
  float*          pe   = (float*)take((size_t)512 * 512 * 4);
  unsigned short* wqkv = (unsigned short*)take((size_t)L_ * 1536 * 512 * 2);
  unsigned short* wot  = (unsigned short*)take((size_t)L_ * 512 * 512 * 2);
  unsigned short* w1t  = (unsigned short*)take((size_t)L_ * 2048 * 512 * 2);
  unsigned short* w2t  = (unsigned short*)take((size_t)L_ * 512 * 2048 * 2);
  unsigned short* xb   = (unsigned short*)take((size_t)M_ * 512 * 2);
  unsigned short* qb   = (unsigned short*)take((size_t)M_ * 512 * 2);
  unsigned short* kb   = (unsigned short*)take((size_t)M_ * 512 * 2);
  unsigned short* vb   = (unsigned short*)take((size_t)M_ * 512 * 2);
  unsigned short* cxb  = (unsigned short*)take((size_t)M_ * 512 * 2);
  unsigned short* hb   = (unsigned short*)take((size_t)M_ * 512 * 2);
  unsigned short* t1   = (unsigned short*)take((size_t)M_ * 512 * 2);
  unsigned short* f1b  = qb;          // alias: q/k/v/cxb region (67 MB contiguous) free during FFN
  float*          part = (float*)qb;  // alias: free after last layer

  pe_kernel<<<1024, 256, 0, stream>>>(pe);
  wconv_kernel<<<dim3(16, 16, L_), 256, 0, stream>>>(Wq, wqkv,          512, 512,  (size_t)1536 * 512);
  wconv_kernel<<<dim3(16, 16, L_), 256, 0, stream>>>(Wk, wqkv + 262144, 512, 512,  (size_t)1536 * 512);
  wconv_kernel<<<dim3(16, 16, L_), 256, 0, stream>>>(Wv, wqkv + 524288, 512, 512,  (size_t)1536 * 512);
  wconv_kernel<<<dim3(16, 16, L_), 256, 0, stream>>>(Wo, wot,           512, 512,  (size_t)512 * 512);
  wconv_kernel<<<dim3(16, 64, L_), 256, 0, stream>>>(W1, w1t,           512, 2048, (size_t)2048 * 512);
  wconv_kernel<<<dim3(64, 16, L_), 256, 0, stream>>>(W2, w2t,           2048, 512, (size_t)512 * 2048);
  embed_kernel<<<M_, 128, 0, stream>>>(x, emb, pe, xb);

  for (int l = 0; l < L_; ++l) {
    // QKV: N=1536 -> nbx=6, grid 768
    gemm_kernel<<<768, 512, 0, stream>>>(
        xb, wqkv + (size_t)l * 1536 * 512,
        bq + l * 512, bk + l * 512, bv + l * 512,
        qb, kb, vb, 512, 1536, 0, 1, 6);
    attn_kernel<<<dim3(4, G_), 256, 0, stream>>>(qb, kb, vb, cxb);
    // O-proj: N=512 -> nbx=2, grid 256 (raw out -> t1)
    gemm_kernel<<<256, 512, 0, stream>>>(
        cxb, wot + (size_t)l * 512 * 512,
        bo + l * 512, nullptr, nullptr,
        t1, nullptr, nullptr, 512, 512, 0, 0, 2);
    addln_kernel<<<M_, 128, 0, stream>>>(t1, xb, g1 + l * 512, bn1 + l * 512, hb);
    // FF1: N=2048 -> nbx=8, grid 1024
    gemm_kernel<<<1024, 512, 0, stream>>>(
        hb, w1t + (size_t)l * 2048 * 512,
        bf1 + l * 2048, nullptr, nullptr,
        f1b, nullptr, nullptr, 512, 2048, 1, 0, 8);
    // FF2: N=512, K=2048 -> nbx=2, grid 256 (raw out -> t1)
    gemm_kernel<<<256, 512, 0, stream>>>(
        f1b, w2t + (size_t)l * 512 * 2048,
        bf2 + l * 512, nullptr, nullptr,
        t1, nullptr, nullptr, 2048, 512, 0, 0, 2);
    addln_kernel<<<M_, 128, 0, stream>>>(t1, hb, g2 + l * 512, bn2 + l * 512, xb);
  }

  fc_part_kernel<<<dim3(4, 256), 256, 0, stream>>>(xb, Wfc, part);
  fc_reduce_kernel<<<dim3(4, 32), 256, 0, stream>>>(part, bfc, out);
}